// Round 14
// baseline (1433.026 us; speedup 1.0000x reference)
//
#include <hip/hip_runtime.h>

// Decoder: B=16, T=128, V=32000, E=512, H=1024 (2 LSTM layers), CTX=2048.
// R14: NO grid barrier — self-validating dataflow rings.
//   Rings (xr, h1r) are write-once and every value is finite bf16 (never
//   0xFFFF = NaN). Rings memset to 0xFF each launch; consumers poll the data
//   itself with sc0/sc1 bypass loads until every u16 half != 0xFFFF.
//   Sync chain per step collapses from store->drain->flag->observe->read
//   (3 fabric RTTs) to store->read (1 visibility hop). Per-word granularity
//   removes the max-over-128-blocks straggler wait.
//   Validity is checked PER U16 HALF (adjacent units written by different
//   threads -> dwords can be half-written).
// dec compute skeleton = R12/R13 (register weights, 14 parallel bursts).
// fc_gemm_bf: bf16 MFMA GEMM (fcw pre-converted once). prep_ctx2 coalesced.

#define NBLK 128

typedef float f32x4 __attribute__((ext_vector_type(4)));
typedef __bf16 bf16x8 __attribute__((ext_vector_type(8)));
typedef unsigned short u16;

__device__ __forceinline__ float sigf(float x) { return 1.0f / (1.0f + __expf(-x)); }
__device__ __forceinline__ float tanh_(float x) {
  x = fminf(15.0f, fmaxf(-15.0f, x));
  float e = __expf(2.0f * x);
  return (e - 1.0f) / (e + 1.0f);
}

__device__ __forceinline__ u16 f2bf(float f) {
  __bf16 h = (__bf16)f;  // RNE; finite input -> never 0xFFFF (NaN pattern)
  return __builtin_bit_cast(u16, h);
}

__device__ __forceinline__ bf16x8 cvt8(float4 a, float4 b) {
  bf16x8 v;
  v[0] = (__bf16)a.x; v[1] = (__bf16)a.y; v[2] = (__bf16)a.z; v[3] = (__bf16)a.w;
  v[4] = (__bf16)b.x; v[5] = (__bf16)b.y; v[6] = (__bf16)b.z; v[7] = (__bf16)b.w;
  return v;
}

// Coherent (write-through) bf16 store.
__device__ __forceinline__ void st_cv16(u16* p, u16 v) {
  unsigned vv = v;
  asm volatile("global_store_short %0, %1, off sc0 sc1" :: "v"(p), "v"(vv) : "memory");
}

// 8 bypass dwordx4 loads in flight, one waitcnt (poll read).
__device__ __forceinline__ void ld8x16_cv(
    const u16* a0, const u16* a1, const u16* a2, const u16* a3,
    const u16* a4, const u16* a5, const u16* a6, const u16* a7,
    uint4& v0, uint4& v1, uint4& v2, uint4& v3,
    uint4& v4, uint4& v5, uint4& v6, uint4& v7) {
  asm volatile(
      "global_load_dwordx4 %0, %8, off sc0 sc1\n\t"
      "global_load_dwordx4 %1, %9, off sc0 sc1\n\t"
      "global_load_dwordx4 %2, %10, off sc0 sc1\n\t"
      "global_load_dwordx4 %3, %11, off sc0 sc1\n\t"
      "global_load_dwordx4 %4, %12, off sc0 sc1\n\t"
      "global_load_dwordx4 %5, %13, off sc0 sc1\n\t"
      "global_load_dwordx4 %6, %14, off sc0 sc1\n\t"
      "global_load_dwordx4 %7, %15, off sc0 sc1\n\t"
      "s_waitcnt vmcnt(0)"
      : "=&v"(v0), "=&v"(v1), "=&v"(v2), "=&v"(v3),
        "=&v"(v4), "=&v"(v5), "=&v"(v6), "=&v"(v7)
      : "v"(a0), "v"(a1), "v"(a2), "v"(a3), "v"(a4), "v"(a5), "v"(a6), "v"(a7)
      : "memory");
}

// All 8 u16 halves written (!= 0xFFFF sentinel)?
__device__ __forceinline__ bool ok16(uint4 v) {
  unsigned bad = 0;
  bad |= ((v.x & 0xFFFFu) == 0xFFFFu); bad |= ((v.x >> 16) == 0xFFFFu);
  bad |= ((v.y & 0xFFFFu) == 0xFFFFu); bad |= ((v.y >> 16) == 0xFFFFu);
  bad |= ((v.z & 0xFFFFu) == 0xFFFFu); bad |= ((v.z >> 16) == 0xFFFFu);
  bad |= ((v.w & 0xFFFFu) == 0xFFFFu); bad |= ((v.w >> 16) == 0xFFFFu);
  return bad == 0;
}

__device__ __forceinline__ void dot4(float& a, float4 wv, float4 xv) {
  a = fmaf(wv.x, xv.x, a);
  a = fmaf(wv.y, xv.y, a);
  a = fmaf(wv.z, xv.z, a);
  a = fmaf(wv.w, xv.w, a);
}

// ---- prep: fp32 -> bf16 contiguous convert (fcw) ----
__global__ void prep_bf16(const float* __restrict__ src, u16* __restrict__ dst, int n8) {
  for (int i = blockIdx.x * blockDim.x + threadIdx.x; i < n8; i += gridDim.x * blockDim.x) {
    float4 a = *(const float4*)(src + (size_t)i * 8);
    float4 b = *(const float4*)(src + (size_t)i * 8 + 4);
    bf16x8 v = cvt8(a, b);
    *(uint4*)(dst + (size_t)i * 8) = __builtin_bit_cast(uint4, v);
  }
}

// ---- prep: gather token embeddings as bf16: x0b[tb][512], tb = t*16+b ----
__global__ void prep_emb(const int* __restrict__ tgt, const float* __restrict__ emb,
                         u16* __restrict__ x0b) {
  const int g = blockIdx.x * blockDim.x + threadIdx.x;  // 131072 total
  const int col8 = (g & 63) * 8;
  const int tb = g >> 6;            // 0..2047
  const int t = tb >> 4, b = tb & 15;
  const int tok = (t == 0) ? 1 : tgt[b * 128 + (t - 1)];
  const float* s = emb + (size_t)tok * 512 + col8;
  float4 a = *(const float4*)s;
  float4 bb = *(const float4*)(s + 4);
  bf16x8 v = cvt8(a, bb);
  *(uint4*)(x0b + (size_t)tb * 512 + col8) = __builtin_bit_cast(uint4, v);
}

// ---- prep: cp[j][b] = sum_k wih0[j][512+k]*ctx[b][k]  (coalesced split-K) --
__global__ __launch_bounds__(256, 1) void prep_ctx2(const float* __restrict__ enc_h,
                                                    const float* __restrict__ wih0,
                                                    float* __restrict__ cp) {
  __shared__ float ctx[16][2052];
  const int tid = threadIdx.x;
#pragma unroll
  for (int c = 0; c < 32; ++c) {
    int f4 = tid + c * 256;
    int b = f4 >> 9, kq = f4 & 511;
    *(float4*)&ctx[b][kq * 4] =
        *(const float4*)(enc_h + (kq >> 7) * 8192 + b * 512 + (kq & 127) * 4);
  }
  __syncthreads();
  const int r = tid >> 4, l = tid & 15;
  const int j = blockIdx.x * 16 + r;
  const float* w = wih0 + (size_t)j * 2560 + 512;
  float acc[16] = {};
#pragma unroll 4
  for (int i = 0; i < 32; ++i) {
    const int k = l * 4 + i * 64;
    const float4 w4 = *(const float4*)(w + k);
#pragma unroll
    for (int b = 0; b < 16; ++b) dot4(acc[b], w4, *(const float4*)&ctx[b][k]);
  }
#pragma unroll
  for (int off = 1; off < 16; off <<= 1)
#pragma unroll
    for (int b = 0; b < 16; ++b) acc[b] += __shfl_xor(acc[b], off);
  cp[(size_t)j * 16 + l] = acc[l];
}

// 16 chained MFMAs; A-frags from LDS slab BP (stride S u16, col off XOFF),
// B-frags from register weights BW[16].
#define BURST(ACC, BP, S, XOFF, BW)                                            \
  _Pragma("unroll")                                                            \
  for (int mm = 0; mm < 16; ++mm) {                                            \
    bf16x8 av = *(const bf16x8*)&(BP)[fr * (S) + (XOFF) + mm * 32 + ks8];      \
    ACC = __builtin_amdgcn_mfma_f32_16x16x32_bf16(av, (BW)[mm], ACC, 0, 0, 0); \
  }

// Load one burst's 16 weight fragments into registers.
// q = c*2 + tile; c: 0 emb(wih0) | 1,2 hh0 k0/k1 | 3,4 ih1 k0/k1 | 5,6 hh1.
__device__ __forceinline__ void loadw(bf16x8* dst, int q, int w8, int lane,
                                      const float* wih0, const float* whh0,
                                      const float* wih1, const float* whh1) {
  const int c = q >> 1, tile = q & 1;
  const int nn = lane & 15;
  const int gate = tile * 2 + (nn >> 3);
  const int unit = nn & 7;
  const int j = gate * 1024 + w8 + unit;
  const float* src;
  size_t stride = 1024;
  int ko = 0;
  if (c == 0) { src = wih0; stride = 2560; ko = 0; }
  else if (c <= 2) { src = whh0; ko = (c - 1) * 512; }
  else if (c <= 4) { src = wih1; ko = (c - 3) * 512; }
  else { src = whh1; ko = (c - 5) * 512; }
  const float* base = src + (size_t)j * stride + ko + ((lane >> 4) * 8);
#pragma unroll
  for (int mm = 0; mm < 16; ++mm) {
    const float* sp = base + mm * 32;
    dst[mm] = cvt8(*(const float4*)sp, *(const float4*)(sp + 4));
  }
}

// ---------------- persistent MFMA decoder: dataflow, no barrier ------------
// Rings (bf16, write-once, sentinel 0xFFFF): xr slot t+1 = h0/x1[t]
// (slot 0 = init h0); h1r slot t+1 = h1[t] (slot 0 = init h1).
__global__ __launch_bounds__(512, 2) void dec_seq_df(
    const float* __restrict__ enc_h, const float* __restrict__ enc_c,
    const float* __restrict__ wih0, const float* __restrict__ whh0,
    const float* __restrict__ wih1, const float* __restrict__ whh1,
    const float* __restrict__ bih0, const float* __restrict__ bhh0,
    const float* __restrict__ bih1, const float* __restrict__ bhh1,
    const float* __restrict__ cp, const u16* __restrict__ x0b,
    u16* __restrict__ xr, u16* __restrict__ h1r,
    u16* __restrict__ out2b) {
  __shared__ u16 xe[16 * 520];       // emb slab (staged ahead)
  __shared__ u16 xs[16 * 1032];      // x slot s
  __shared__ u16 h1s[16 * 1032];     // h1 slot s-1
  __shared__ float gls[14][16][17];  // partial acc tiles [q][n][batch]

  const int tid = threadIdx.x;
  const int wgid = blockIdx.x;
  const int w8 = wgid * 8;
  const int lane = tid & 63;
  const int wave = tid >> 6;
  const int fr = lane & 15;
  const int ks8 = (lane >> 4) * 8;

  bf16x8 bw0[16], bw1[16];
  const int q0 = (wave < 6) ? 2 * wave : (wave == 6 ? 12 : 13);
  loadw(bw0, q0, w8, lane, wih0, whh0, wih1, whh1);
  if (wave < 6) loadw(bw1, 2 * wave + 1, w8, lane, wih0, whh0, wih1, whh1);
  else {
#pragma unroll
    for (int mm = 0; mm < 16; ++mm) bw1[mm] = bf16x8{};
  }

  const int gdj = (tid >> 4) & 7;
  const int gb = tid & 15;
  float cpA0 = 0.f, cpA1 = 0.f, cpA2 = 0.f, cpA3 = 0.f;
  float cpB0 = 0.f, cpB1 = 0.f, cpB2 = 0.f, cpB3 = 0.f;
  float c0r = 0.f, c1r = 0.f;
  if (tid < 128) {
    const int jp = w8 + gdj;
    cpA0 = cp[(size_t)(jp) * 16 + gb] + bih0[jp] + bhh0[jp];
    cpA1 = cp[(size_t)(1024 + jp) * 16 + gb] + bih0[1024 + jp] + bhh0[1024 + jp];
    cpA2 = cp[(size_t)(2048 + jp) * 16 + gb] + bih0[2048 + jp] + bhh0[2048 + jp];
    cpA3 = cp[(size_t)(3072 + jp) * 16 + gb] + bih0[3072 + jp] + bhh0[3072 + jp];
    cpB0 = bih1[jp] + bhh1[jp];
    cpB1 = bih1[1024 + jp] + bhh1[1024 + jp];
    cpB2 = bih1[2048 + jp] + bhh1[2048 + jp];
    cpB3 = bih1[3072 + jp] + bhh1[3072 + jp];
    const int dir = jp >> 9, e = jp & 511;
    c0r = enc_c[dir * 8192 + gb * 512 + e];
    c1r = enc_c[(2 + dir) * 8192 + gb * 512 + e];
    // slot-0 ring init (coherent stores; consumers poll until visible)
    st_cv16(xr + gb * 1024 + jp, f2bf(enc_h[dir * 8192 + gb * 512 + e]));
    st_cv16(h1r + gb * 1024 + jp, f2bf(enc_h[(2 + dir) * 8192 + gb * 512 + e]));
  }

  const int sm = tid >> 5;
  const int skq = (tid & 31) * 8;

  // pre-stage emb slab for s=0 (static input; plain cached loads)
  {
    const u16* se = x0b + sm * 512;
#pragma unroll
    for (int jj = 0; jj < 2; ++jj)
      *(uint4*)&xe[sm * 520 + skq + jj * 256] = *(const uint4*)(se + skq + jj * 256);
  }

  // ---- MAIN LOOP: 129 steps; A = L0[t=s], B = L1[t=s-1]; sync = dataflow ----
  for (int s = 0; s < 129; ++s) {
    const bool doA = (s < 128), doB = (s >= 1);

    // prefetch next emb slab (static; plain cached)
    uint4 re[2] = {};
    if (s < 127) {
      const u16* se = x0b + (size_t)(s + 1) * 8192 + sm * 512;
#pragma unroll
      for (int jj = 0; jj < 2; ++jj) re[jj] = *(const uint4*)(se + skq + jj * 256);
    }

    // dataflow poll: bypass-read ring slabs until all u16 halves valid
    const u16* sx = xr + (size_t)s * 16384 + sm * 1024 + skq;
    const u16* sh = h1r + (size_t)(doB ? (s - 1) : 0) * 16384 + sm * 1024 + skq;
    uint4 X0, X1, X2, X3, H0, H1, H2, H3;
    for (;;) {
      ld8x16_cv(sx, sx + 256, sx + 512, sx + 768, sh, sh + 256, sh + 512, sh + 768,
                X0, X1, X2, X3, H0, H1, H2, H3);
      bool ok = ok16(X0) & ok16(X1) & ok16(X2) & ok16(X3);
      if (doB) ok = ok & ok16(H0) & ok16(H1) & ok16(H2) & ok16(H3);
      if (ok) break;
      __builtin_amdgcn_s_sleep(1);
    }
    *(uint4*)&xs[sm * 1032 + skq] = X0;
    *(uint4*)&xs[sm * 1032 + skq + 256] = X1;
    *(uint4*)&xs[sm * 1032 + skq + 512] = X2;
    *(uint4*)&xs[sm * 1032 + skq + 768] = X3;
    if (doB) {
      *(uint4*)&h1s[sm * 1032 + skq] = H0;
      *(uint4*)&h1s[sm * 1032 + skq + 256] = H1;
      *(uint4*)&h1s[sm * 1032 + skq + 512] = H2;
      *(uint4*)&h1s[sm * 1032 + skq + 768] = H3;
    }
    __syncthreads();

    // 14 bursts over 8 waves
    f32x4 acc0 = {0.f, 0.f, 0.f, 0.f}, acc1 = {0.f, 0.f, 0.f, 0.f};
    bool act0 = false, act1 = false;
    if (wave == 0) { if (doA) { BURST(acc0, xe, 520, 0, bw0) BURST(acc1, xe, 520, 0, bw1) act0 = act1 = true; } }
    else if (wave == 1) { if (doA) { BURST(acc0, xs, 1032, 0, bw0) BURST(acc1, xs, 1032, 0, bw1) act0 = act1 = true; } }
    else if (wave == 2) { if (doA) { BURST(acc0, xs, 1032, 512, bw0) BURST(acc1, xs, 1032, 512, bw1) act0 = act1 = true; } }
    else if (wave == 3) { if (doB) { BURST(acc0, xs, 1032, 0, bw0) BURST(acc1, xs, 1032, 0, bw1) act0 = act1 = true; } }
    else if (wave == 4) { if (doB) { BURST(acc0, xs, 1032, 512, bw0) BURST(acc1, xs, 1032, 512, bw1) act0 = act1 = true; } }
    else if (wave == 5) { if (doB) { BURST(acc0, h1s, 1032, 0, bw0) BURST(acc1, h1s, 1032, 0, bw1) act0 = act1 = true; } }
    else if (wave == 6) { if (doB) { BURST(acc0, h1s, 1032, 512, bw0) act0 = true; } }
    else { if (doB) { BURST(acc0, h1s, 1032, 512, bw0) act0 = true; } }
    if (act0) {
#pragma unroll
      for (int r = 0; r < 4; ++r) gls[q0][fr][(lane >> 4) * 4 + r] = acc0[r];
    }
    if (act1) {
#pragma unroll
      for (int r = 0; r < 4; ++r) gls[q0 + 1][fr][(lane >> 4) * 4 + r] = acc1[r];
    }
    __syncthreads();

    // stage next emb slab (xe consumed by this step's bursts)
    if (s < 127) {
#pragma unroll
      for (int jj = 0; jj < 2; ++jj) *(uint4*)&xe[sm * 520 + skq + jj * 256] = re[jj];
    }

    // epilogue: gate math + coherent ring stores (no drain, no flag)
    if (tid < 128) {
      const int jp = w8 + gdj;
      if (doA) {
        float gi = gls[0][gdj][gb] + gls[2][gdj][gb] + gls[4][gdj][gb] + cpA0;
        float gf = gls[0][8 + gdj][gb] + gls[2][8 + gdj][gb] + gls[4][8 + gdj][gb] + cpA1;
        float gg = gls[1][gdj][gb] + gls[3][gdj][gb] + gls[5][gdj][gb] + cpA2;
        float go = gls[1][8 + gdj][gb] + gls[3][8 + gdj][gb] + gls[5][8 + gdj][gb] + cpA3;
        c0r = sigf(gf) * c0r + sigf(gi) * tanh_(gg);
        float h = sigf(go) * tanh_(c0r);
        st_cv16(xr + (size_t)(s + 1) * 16384 + gb * 1024 + jp, f2bf(h));
      }
      if (doB) {
        float gi = gls[6][gdj][gb] + gls[8][gdj][gb] + gls[10][gdj][gb] +
                   gls[12][gdj][gb] + cpB0;
        float gf = gls[6][8 + gdj][gb] + gls[8][8 + gdj][gb] + gls[10][8 + gdj][gb] +
                   gls[12][8 + gdj][gb] + cpB1;
        float gg = gls[7][gdj][gb] + gls[9][gdj][gb] + gls[11][gdj][gb] +
                   gls[13][gdj][gb] + cpB2;
        float go = gls[7][8 + gdj][gb] + gls[9][8 + gdj][gb] + gls[11][8 + gdj][gb] +
                   gls[13][8 + gdj][gb] + cpB3;
        c1r = sigf(gf) * c1r + sigf(gi) * tanh_(gg);
        float h = sigf(go) * tanh_(c1r);
        st_cv16(h1r + (size_t)s * 16384 + gb * 1024 + jp, f2bf(h));
        out2b[((s - 1) * 16 + gb) * 1024 + jp] = f2bf(tanh_(h));
      }
    }
  }
}

// logits GEMM, B already bf16: A [2048][1024] bf16, Bwb [32000][1024] bf16.
__global__ __launch_bounds__(256, 2) void fc_gemm_bf(
    const u16* __restrict__ A, const u16* __restrict__ Bwb,
    const float* __restrict__ bias, float* __restrict__ C) {
  __shared__ __align__(16) u16 Al[128][40];
  __shared__ __align__(16) u16 Bl[128][40];

  const int tid = threadIdx.x;
  const int m0 = blockIdx.x * 128;
  const int n0 = blockIdx.y * 128;
  const int wave = tid >> 6;
  const int lane = tid & 63;
  const int wm = (wave & 1) * 64;
  const int wn = (wave >> 1) * 64;
  const int fr = lane & 15;
  const int ks = lane >> 4;
  const int srow = tid >> 1;
  const int sh16 = (tid & 1) * 16;

  const u16* Ag = A + (size_t)(m0 + srow) * 1024 + sh16;
  const u16* Bg = Bwb + (size_t)(n0 + srow) * 1024 + sh16;

  f32x4 acc[4][4] = {};

  for (int k0 = 0; k0 < 1024; k0 += 32) {
    uint4 a0 = *(const uint4*)(Ag + k0);
    uint4 a1 = *(const uint4*)(Ag + k0 + 8);
    uint4 b0 = *(const uint4*)(Bg + k0);
    uint4 b1 = *(const uint4*)(Bg + k0 + 8);

    __syncthreads();
    *(uint4*)&Al[srow][sh16] = a0;
    *(uint4*)&Al[srow][sh16 + 8] = a1;
    *(uint4*)&Bl[srow][sh16] = b0;
    *(uint4*)&Bl[srow][sh16 + 8] = b1;
    __syncthreads();

    bf16x8 af[4], bf[4];
#pragma unroll
    for (int i = 0; i < 4; ++i) af[i] = *(const bf16x8*)&Al[wm + i * 16 + fr][ks * 8];
#pragma unroll
    for (int j = 0; j < 4; ++j) bf[j] = *(const bf16x8*)&Bl[wn + j * 16 + fr][ks * 8];
#pragma unroll
    for (int i = 0; i < 4; ++i)
#pragma unroll
      for (int j = 0; j < 4; ++j)
        acc[i][j] = __builtin_amdgcn_mfma_f32_16x16x32_bf16(af[i], bf[j], acc[i][j], 0, 0, 0);
  }

  float bj[4];
#pragma unroll
  for (int j = 0; j < 4; ++j) bj[j] = bias[n0 + wn + j * 16 + fr];

  const int mrb = (lane >> 4) * 4;
#pragma unroll
  for (int i = 0; i < 4; ++i) {
#pragma unroll
    for (int r = 0; r < 4; ++r) {
      const int m = m0 + wm + i * 16 + mrb + r;
      float* dst = C + ((size_t)(m & 15) * 128 + (m >> 4)) * 32000;
#pragma unroll
      for (int j = 0; j < 4; ++j) {
        dst[n0 + wn + j * 16 + fr] = acc[i][j][r] + bj[j];
      }
    }
  }
}

// fallback fc (fp32 B, converts per tile) — used if ws too small for fcwb.
__global__ __launch_bounds__(256, 2) void fc_gemm_mfma(
    const u16* __restrict__ A, const float* __restrict__ Bw,
    const float* __restrict__ bias, float* __restrict__ C) {
  __shared__ __align__(16) u16 Al[128][40];
  __shared__ __align__(16) u16 Bl[128][40];
  const int tid = threadIdx.x;
  const int m0 = blockIdx.x * 128;
  const int n0 = blockIdx.y * 128;
  const int wave = tid >> 6;
  const int lane = tid & 63;
  const int wm = (wave & 1) * 64;
  const int wn = (wave >> 1) * 64;
  const int fr = lane & 15;
  const int ks = lane >> 4;
  const int srow = tid >> 1;
  const int sh16 = (tid & 1) * 16;
  const u16* Ag = A + (size_t)(m0 + srow) * 1024 + sh16;
  const float* Bg = Bw + (size_t)(n0 + srow) * 1024 + sh16;
  f32x4 acc[4][4] = {};
  for (int k0 = 0; k0 < 1024; k0 += 32) {
    uint4 a0 = *(const uint4*)(Ag + k0);
    uint4 a1 = *(const uint4*)(Ag + k0 + 8);
    float bfv[16];
    *(float4*)&bfv[0] = *(const float4*)(Bg + k0);
    *(float4*)&bfv[4] = *(const float4*)(Bg + k0 + 4);
    *(float4*)&bfv[8] = *(const float4*)(Bg + k0 + 8);
    *(float4*)&bfv[12] = *(const float4*)(Bg + k0 + 12);
    u16 bu[16];
#pragma unroll
    for (int u = 0; u < 16; ++u) bu[u] = f2bf(bfv[u]);
    __syncthreads();
    *(uint4*)&Al[srow][sh16] = a0;
    *(uint4*)&Al[srow][sh16 + 8] = a1;
    *(uint4*)&Bl[srow][sh16] = *(uint4*)&bu[0];
    *(uint4*)&Bl[srow][sh16 + 8] = *(uint4*)&bu[8];
    __syncthreads();
    bf16x8 af[4], bf[4];
#pragma unroll
    for (int i = 0; i < 4; ++i) af[i] = *(const bf16x8*)&Al[wm + i * 16 + fr][ks * 8];
#pragma unroll
    for (int j = 0; j < 4; ++j) bf[j] = *(const bf16x8*)&Bl[wn + j * 16 + fr][ks * 8];
#pragma unroll
    for (int i = 0; i < 4; ++i)
#pragma unroll
      for (int j = 0; j < 4; ++j)
        acc[i][j] = __builtin_amdgcn_mfma_f32_16x16x32_bf16(af[i], bf[j], acc[i][j], 0, 0, 0);
  }
  float bj[4];
#pragma unroll
  for (int j = 0; j < 4; ++j) bj[j] = bias[n0 + wn + j * 16 + fr];
  const int mrb = (lane >> 4) * 4;
#pragma unroll
  for (int i = 0; i < 4; ++i) {
#pragma unroll
    for (int r = 0; r < 4; ++r) {
      const int m = m0 + wm + i * 16 + mrb + r;
      float* dst = C + ((size_t)(m & 15) * 128 + (m >> 4)) * 32000;
#pragma unroll
      for (int j = 0; j < 4; ++j) dst[n0 + wn + j * 16 + fr] = acc[i][j][r] + bj[j];
    }
  }
}

extern "C" void kernel_launch(void* const* d_in, const int* in_sizes, int n_in,
                              void* d_out, int out_size, void* d_ws, size_t ws_size,
                              hipStream_t stream) {
  const float* enc_h = (const float*)d_in[0];
  const float* enc_c = (const float*)d_in[1];
  const int* tgt = (const int*)d_in[2];
  const float* emb = (const float*)d_in[3];
  const float* wih0 = (const float*)d_in[4];
  const float* whh0 = (const float*)d_in[5];
  const float* bih0 = (const float*)d_in[6];
  const float* bhh0 = (const float*)d_in[7];
  const float* wih1 = (const float*)d_in[8];
  const float* whh1 = (const float*)d_in[9];
  const float* bih1 = (const float*)d_in[10];
  const float* bhh1 = (const float*)d_in[11];
  const float* fcw = (const float*)d_in[12];
  const float* fcb = (const float*)d_in[13];
  float* logits = (float*)d_out;

  // ws layout: pad 32K | cp 256K | x0b 2M | xr 4.125M | h1r 4.125M |
  //            out2b 4M | fcwb 65.5M  (total ~80.6 MB)
  float* cp = (float*)((char*)d_ws + 32768);
  u16* x0b = (u16*)(cp + 65536);
  u16* xr = x0b + 1048576;
  u16* h1r = xr + 2113536;
  u16* out2b = h1r + 2113536;
  u16* fcwb = out2b + 2097152;
  const bool use_bf_fc = (ws_size >= 80576512ull);

  // sentinel-fill both rings (0xFFFF = NaN bf16, never produced by compute);
  // REQUIRED every launch: replays would otherwise see stale valid-looking data
  hipMemsetAsync(xr, 0xFF, 2 * 2113536 * sizeof(u16), stream);

  prep_emb<<<512, 256, 0, stream>>>(tgt, emb, x0b);
  prep_ctx2<<<256, 256, 0, stream>>>(enc_h, wih0, cp);
  if (use_bf_fc)
    prep_bf16<<<2048, 256, 0, stream>>>(fcw, fcwb, 4096000);
  dec_seq_df<<<NBLK, 512, 0, stream>>>(enc_h, enc_c, wih0, whh0, wih1, whh1,
                                       bih0, bhh0, bih1, bhh1, cp, x0b,
                                       xr, h1r, out2b);
  if (use_bf_fc)
    fc_gemm_bf<<<dim3(16, 250), 256, 0, stream>>>(out2b, fcwb, fcb, logits);
  else
    fc_gemm_mfma<<<dim3(16, 250), 256, 0, stream>>>(out2b, fcw, fcb, logits);
}

// Round 15
// 986.728 us; speedup vs baseline: 1.4523x; 1.4523x over previous
//
#include <hip/hip_runtime.h>

// Decoder: B=16, T=128, V=32000, E=512, H=1024 (2 LSTM layers), CTX=2048.
// R15: FUSED dec + fc in one launch.
//   - dec path (blocks 0..127): R13's proven skeleton (register weights, 14
//     parallel MFMA bursts, flat flag barrier, 736us). out2b stores are now
//     WRITE-THROUGH (sc0 sc1) so fc blocks on other XCDs can consume in-kernel.
//   - fc path (blocks 128..252): each owns a private 256-row vocab slice;
//     converts its fcw slice to bf16 (replaces prep_bf16 kernel), then computes
//     its 16 (128m x 256n) logits tiles in t-order, gated on dec's barrier
//     flags (flags >= m0*8+10 => out2 rows written AND drained). A-tiles read
//     with bypass loads (no L2 stale/prefetch hazard). Runs entirely in the
//     shadow of dec's 736us on the 128 otherwise-idle CUs.
//   - LDS overlaid between paths (max 98KB) -> 1 block/CU, 253 blocks resident.
//   R14 post-mortem: data-wide sentinel polling moved 64KB/block/round through
//   MALL (vs 32KB/grid for flags) -> +3.4us/step. Reverted to flag barrier.

#define NBLK 128
#define NFCB 125

typedef float f32x4 __attribute__((ext_vector_type(4)));
typedef __bf16 bf16x8 __attribute__((ext_vector_type(8)));
typedef unsigned short u16;

__device__ __forceinline__ float sigf(float x) { return 1.0f / (1.0f + __expf(-x)); }
__device__ __forceinline__ float tanh_(float x) {
  x = fminf(15.0f, fmaxf(-15.0f, x));
  float e = __expf(2.0f * x);
  return (e - 1.0f) / (e + 1.0f);
}

__device__ __forceinline__ u16 f2bf(float f) {
  __bf16 h = (__bf16)f;  // RNE
  return __builtin_bit_cast(u16, h);
}

__device__ __forceinline__ bf16x8 cvt8(float4 a, float4 b) {
  bf16x8 v;
  v[0] = (__bf16)a.x; v[1] = (__bf16)a.y; v[2] = (__bf16)a.z; v[3] = (__bf16)a.w;
  v[4] = (__bf16)b.x; v[5] = (__bf16)b.y; v[6] = (__bf16)b.z; v[7] = (__bf16)b.w;
  return v;
}

// Coherent (write-through) bf16 store.
__device__ __forceinline__ void st_cv16(u16* p, u16 v) {
  unsigned vv = v;
  asm volatile("global_store_short %0, %1, off sc0 sc1" :: "v"(p), "v"(vv) : "memory");
}

// Plain sc0/sc1 flag store (caller guarantees data already drained).
__device__ __forceinline__ void flag_store(unsigned* p, unsigned v) {
  asm volatile("global_store_dword %0, %1, off sc0 sc1" :: "v"(p), "v"(v) : "memory");
}

// 2 bypass flag loads in flight (no atomic lowering -> no buffer_inv).
__device__ __forceinline__ void ld2_flags(const unsigned* p0, const unsigned* p1,
                                          unsigned& a, unsigned& b) {
  asm volatile(
      "global_load_dword %0, %2, off sc0 sc1\n\t"
      "global_load_dword %1, %3, off sc0 sc1\n\t"
      "s_waitcnt vmcnt(0)"
      : "=&v"(a), "=&v"(b)
      : "v"(p0), "v"(p1)
      : "memory");
}

// Bypass dwordx4 load with fused wait (cross-XCD fresh data).
__device__ __forceinline__ void ld1_cv(const u16* p, uint4& v) {
  asm volatile(
      "global_load_dwordx4 %0, %1, off sc0 sc1\n\t"
      "s_waitcnt vmcnt(0)"
      : "=&v"(v) : "v"(p) : "memory");
}

// Flat one-hop barrier: all threads drain stores, block flag (own 128B line),
// wave0 polls 2 flags/lane.
__device__ __forceinline__ void gsyncf(unsigned step, unsigned* bar) {
  asm volatile("s_waitcnt vmcnt(0)" ::: "memory");
  __syncthreads();
  const int tid = threadIdx.x;
  if (tid == 0) flag_store(bar + 32 + blockIdx.x * 32, step);
  if (tid < 64) {
    const unsigned* p0 = bar + 32 + tid * 64;   // block 2*tid
    const unsigned* p1 = p0 + 32;               // block 2*tid+1
    for (;;) {
      unsigned a, b;
      ld2_flags(p0, p1, a, b);
      if (__all((a >= step) & (b >= step))) break;
      __builtin_amdgcn_s_sleep(1);
    }
    asm volatile("" ::: "memory");
  }
  __syncthreads();
}

// fc-side wait: all 128 dec flags >= target.
__device__ __forceinline__ void wait_flags(unsigned target, const unsigned* bar) {
  const int tid = threadIdx.x;
  if (tid < 64) {
    const unsigned* p0 = bar + 32 + tid * 64;
    const unsigned* p1 = p0 + 32;
    for (;;) {
      unsigned a, b;
      ld2_flags(p0, p1, a, b);
      if (__all((a >= target) & (b >= target))) break;
      __builtin_amdgcn_s_sleep(4);
    }
    asm volatile("" ::: "memory");
  }
  __syncthreads();
}

__device__ __forceinline__ void dot4(float& a, float4 wv, float4 xv) {
  a = fmaf(wv.x, xv.x, a);
  a = fmaf(wv.y, xv.y, a);
  a = fmaf(wv.z, xv.z, a);
  a = fmaf(wv.w, xv.w, a);
}

// ---- prep: gather token embeddings as bf16: x0b[tb][512], tb = t*16+b ----
__global__ void prep_emb(const int* __restrict__ tgt, const float* __restrict__ emb,
                         u16* __restrict__ x0b) {
  const int g = blockIdx.x * blockDim.x + threadIdx.x;  // 131072 total
  const int col8 = (g & 63) * 8;
  const int tb = g >> 6;            // 0..2047
  const int t = tb >> 4, b = tb & 15;
  const int tok = (t == 0) ? 1 : tgt[b * 128 + (t - 1)];
  const float* s = emb + (size_t)tok * 512 + col8;
  float4 a = *(const float4*)s;
  float4 bb = *(const float4*)(s + 4);
  bf16x8 v = cvt8(a, bb);
  *(uint4*)(x0b + (size_t)tb * 512 + col8) = __builtin_bit_cast(uint4, v);
}

// ---- prep: cp[j][b] = sum_k wih0[j][512+k]*ctx[b][k]  (coalesced split-K) --
__global__ __launch_bounds__(256, 1) void prep_ctx2(const float* __restrict__ enc_h,
                                                    const float* __restrict__ wih0,
                                                    float* __restrict__ cp) {
  __shared__ float ctx[16][2052];
  const int tid = threadIdx.x;
#pragma unroll
  for (int c = 0; c < 32; ++c) {
    int f4 = tid + c * 256;
    int b = f4 >> 9, kq = f4 & 511;
    *(float4*)&ctx[b][kq * 4] =
        *(const float4*)(enc_h + (kq >> 7) * 8192 + b * 512 + (kq & 127) * 4);
  }
  __syncthreads();
  const int r = tid >> 4, l = tid & 15;
  const int j = blockIdx.x * 16 + r;
  const float* w = wih0 + (size_t)j * 2560 + 512;
  float acc[16] = {};
#pragma unroll 4
  for (int i = 0; i < 32; ++i) {
    const int k = l * 4 + i * 64;
    const float4 w4 = *(const float4*)(w + k);
#pragma unroll
    for (int b = 0; b < 16; ++b) dot4(acc[b], w4, *(const float4*)&ctx[b][k]);
  }
#pragma unroll
  for (int off = 1; off < 16; off <<= 1)
#pragma unroll
    for (int b = 0; b < 16; ++b) acc[b] += __shfl_xor(acc[b], off);
  cp[(size_t)j * 16 + l] = acc[l];
}

// 16 chained MFMAs; A-frags from LDS slab BP (stride S u16, col off XOFF),
// B-frags from register weights BW[16].
#define BURST(ACC, BP, S, XOFF, BW)                                            \
  _Pragma("unroll")                                                            \
  for (int mm = 0; mm < 16; ++mm) {                                            \
    bf16x8 av = *(const bf16x8*)&(BP)[fr * (S) + (XOFF) + mm * 32 + ks8];      \
    ACC = __builtin_amdgcn_mfma_f32_16x16x32_bf16(av, (BW)[mm], ACC, 0, 0, 0); \
  }

// Load one burst's 16 weight fragments into registers.
__device__ __forceinline__ void loadw(bf16x8* dst, int q, int w8, int lane,
                                      const float* wih0, const float* whh0,
                                      const float* wih1, const float* whh1) {
  const int c = q >> 1, tile = q & 1;
  const int nn = lane & 15;
  const int gate = tile * 2 + (nn >> 3);
  const int unit = nn & 7;
  const int j = gate * 1024 + w8 + unit;
  const float* src;
  size_t stride = 1024;
  int ko = 0;
  if (c == 0) { src = wih0; stride = 2560; ko = 0; }
  else if (c <= 2) { src = whh0; ko = (c - 1) * 512; }
  else if (c <= 4) { src = wih1; ko = (c - 3) * 512; }
  else { src = whh1; ko = (c - 5) * 512; }
  const float* base = src + (size_t)j * stride + ko + ((lane >> 4) * 8);
#pragma unroll
  for (int mm = 0; mm < 16; ++mm) {
    const float* sp = base + mm * 32;
    dst[mm] = cvt8(*(const float4*)sp, *(const float4*)(sp + 4));
  }
}

// ---------------- FUSED persistent decoder + shadow logits GEMM -----------
__global__ __launch_bounds__(512, 1) void dec_fc(
    const float* __restrict__ enc_h, const float* __restrict__ enc_c,
    const float* __restrict__ wih0, const float* __restrict__ whh0,
    const float* __restrict__ wih1, const float* __restrict__ whh1,
    const float* __restrict__ bih0, const float* __restrict__ bhh0,
    const float* __restrict__ bih1, const float* __restrict__ bhh1,
    const float* __restrict__ cp, const u16* __restrict__ x0b,
    u16* __restrict__ xr, u16* __restrict__ h1r, u16* __restrict__ out2b,
    const float* __restrict__ fcw, const float* __restrict__ fcb,
    u16* __restrict__ fcwb, float* __restrict__ logits, unsigned* bar) {
  // overlaid shared memory: dec uses 97920B; fc uses 30720B
  __shared__ __align__(16) char smem[97920];

  const int tid = threadIdx.x;
  const int wgid = blockIdx.x;
  const int lane = tid & 63;
  const int wave = tid >> 6;
  const int fr = lane & 15;
  const int ks8 = (lane >> 4) * 8;

  if (wgid < NBLK) {
    // ======================= dec path (R13 skeleton) =======================
    u16* xe = (u16*)smem;                       // 16*520
    u16* xs = xe + 16 * 520;                    // 16*1032
    u16* h1s = xs + 16 * 1032;                  // 16*1032
    float (*gls)[16][17] = (float(*)[16][17])(h1s + 16 * 1032);  // [14][16][17]

    const int w8 = wgid * 8;
    unsigned step = 0;

    bf16x8 bw0[16], bw1[16];
    const int q0 = (wave < 6) ? 2 * wave : (wave == 6 ? 12 : 13);
    loadw(bw0, q0, w8, lane, wih0, whh0, wih1, whh1);
    if (wave < 6) loadw(bw1, 2 * wave + 1, w8, lane, wih0, whh0, wih1, whh1);
    else {
#pragma unroll
      for (int mm = 0; mm < 16; ++mm) bw1[mm] = bf16x8{};
    }

    const int gdj = (tid >> 4) & 7;
    const int gb = tid & 15;
    float cpA0 = 0.f, cpA1 = 0.f, cpA2 = 0.f, cpA3 = 0.f;
    float cpB0 = 0.f, cpB1 = 0.f, cpB2 = 0.f, cpB3 = 0.f;
    float c0r = 0.f, c1r = 0.f;
    if (tid < 128) {
      const int jp = w8 + gdj;
      cpA0 = cp[(size_t)(jp) * 16 + gb] + bih0[jp] + bhh0[jp];
      cpA1 = cp[(size_t)(1024 + jp) * 16 + gb] + bih0[1024 + jp] + bhh0[1024 + jp];
      cpA2 = cp[(size_t)(2048 + jp) * 16 + gb] + bih0[2048 + jp] + bhh0[2048 + jp];
      cpA3 = cp[(size_t)(3072 + jp) * 16 + gb] + bih0[3072 + jp] + bhh0[3072 + jp];
      cpB0 = bih1[jp] + bhh1[jp];
      cpB1 = bih1[1024 + jp] + bhh1[1024 + jp];
      cpB2 = bih1[2048 + jp] + bhh1[2048 + jp];
      cpB3 = bih1[3072 + jp] + bhh1[3072 + jp];
      const int dir = jp >> 9, e = jp & 511;
      c0r = enc_c[dir * 8192 + gb * 512 + e];
      c1r = enc_c[(2 + dir) * 8192 + gb * 512 + e];
      st_cv16(xr + gb * 1024 + jp, f2bf(enc_h[dir * 8192 + gb * 512 + e]));
      st_cv16(h1r + gb * 1024 + jp, f2bf(enc_h[(2 + dir) * 8192 + gb * 512 + e]));
    }

    const int sm = tid >> 5;
    const int skq = (tid & 31) * 8;

    {
      const u16* se = x0b + sm * 512;
#pragma unroll
      for (int jj = 0; jj < 2; ++jj)
        *(uint4*)&xe[sm * 520 + skq + jj * 256] = *(const uint4*)(se + skq + jj * 256);
    }
    gsyncf(++step, bar);

    for (int s = 0; s < 129; ++s) {
      const bool doA = (s < 128), doB = (s >= 1);

      uint4 rx[4], rh[4] = {}, re[2] = {};
      {
        const u16* sx = xr + (size_t)s * 16384 + sm * 1024;
#pragma unroll
        for (int jj = 0; jj < 4; ++jj) rx[jj] = *(const uint4*)(sx + skq + jj * 256);
        if (doB) {
          const u16* sh = h1r + (size_t)(s - 1) * 16384 + sm * 1024;
#pragma unroll
          for (int jj = 0; jj < 4; ++jj) rh[jj] = *(const uint4*)(sh + skq + jj * 256);
        }
        if (s < 127) {
          const u16* se = x0b + (size_t)(s + 1) * 8192 + sm * 512;
#pragma unroll
          for (int jj = 0; jj < 2; ++jj) re[jj] = *(const uint4*)(se + skq + jj * 256);
        }
      }
#pragma unroll
      for (int jj = 0; jj < 4; ++jj) *(uint4*)&xs[sm * 1032 + skq + jj * 256] = rx[jj];
      if (doB) {
#pragma unroll
        for (int jj = 0; jj < 4; ++jj) *(uint4*)&h1s[sm * 1032 + skq + jj * 256] = rh[jj];
      }
      __syncthreads();

      f32x4 acc0 = {0.f, 0.f, 0.f, 0.f}, acc1 = {0.f, 0.f, 0.f, 0.f};
      bool act0 = false, act1 = false;
      if (wave == 0) { if (doA) { BURST(acc0, xe, 520, 0, bw0) BURST(acc1, xe, 520, 0, bw1) act0 = act1 = true; } }
      else if (wave == 1) { if (doA) { BURST(acc0, xs, 1032, 0, bw0) BURST(acc1, xs, 1032, 0, bw1) act0 = act1 = true; } }
      else if (wave == 2) { if (doA) { BURST(acc0, xs, 1032, 512, bw0) BURST(acc1, xs, 1032, 512, bw1) act0 = act1 = true; } }
      else if (wave == 3) { if (doB) { BURST(acc0, xs, 1032, 0, bw0) BURST(acc1, xs, 1032, 0, bw1) act0 = act1 = true; } }
      else if (wave == 4) { if (doB) { BURST(acc0, xs, 1032, 512, bw0) BURST(acc1, xs, 1032, 512, bw1) act0 = act1 = true; } }
      else if (wave == 5) { if (doB) { BURST(acc0, h1s, 1032, 0, bw0) BURST(acc1, h1s, 1032, 0, bw1) act0 = act1 = true; } }
      else if (wave == 6) { if (doB) { BURST(acc0, h1s, 1032, 512, bw0) act0 = true; } }
      else { if (doB) { BURST(acc0, h1s, 1032, 512, bw0) act0 = true; } }
      if (act0) {
#pragma unroll
        for (int r = 0; r < 4; ++r) gls[q0][fr][(lane >> 4) * 4 + r] = acc0[r];
      }
      if (act1) {
#pragma unroll
        for (int r = 0; r < 4; ++r) gls[q0 + 1][fr][(lane >> 4) * 4 + r] = acc1[r];
      }
      __syncthreads();

      if (s < 127) {
#pragma unroll
        for (int jj = 0; jj < 2; ++jj) *(uint4*)&xe[sm * 520 + skq + jj * 256] = re[jj];
      }

      if (tid < 128) {
        const int jp = w8 + gdj;
        if (doA) {
          float gi = gls[0][gdj][gb] + gls[2][gdj][gb] + gls[4][gdj][gb] + cpA0;
          float gf = gls[0][8 + gdj][gb] + gls[2][8 + gdj][gb] + gls[4][8 + gdj][gb] + cpA1;
          float gg = gls[1][gdj][gb] + gls[3][gdj][gb] + gls[5][gdj][gb] + cpA2;
          float go = gls[1][8 + gdj][gb] + gls[3][8 + gdj][gb] + gls[5][8 + gdj][gb] + cpA3;
          c0r = sigf(gf) * c0r + sigf(gi) * tanh_(gg);
          float h = sigf(go) * tanh_(c0r);
          st_cv16(xr + (size_t)(s + 1) * 16384 + gb * 1024 + jp, f2bf(h));
        }
        if (doB) {
          float gi = gls[6][gdj][gb] + gls[8][gdj][gb] + gls[10][gdj][gb] +
                     gls[12][gdj][gb] + cpB0;
          float gf = gls[6][8 + gdj][gb] + gls[8][8 + gdj][gb] + gls[10][8 + gdj][gb] +
                     gls[12][8 + gdj][gb] + cpB1;
          float gg = gls[7][gdj][gb] + gls[9][gdj][gb] + gls[11][gdj][gb] +
                     gls[13][gdj][gb] + cpB2;
          float go = gls[7][8 + gdj][gb] + gls[9][8 + gdj][gb] + gls[11][8 + gdj][gb] +
                     gls[13][8 + gdj][gb] + cpB3;
          c1r = sigf(gf) * c1r + sigf(gi) * tanh_(gg);
          float h = sigf(go) * tanh_(c1r);
          st_cv16(h1r + (size_t)s * 16384 + gb * 1024 + jp, f2bf(h));
          // WRITE-THROUGH: fc blocks on other XCDs consume within this kernel
          st_cv16(out2b + ((s - 1) * 16 + gb) * 1024 + jp, f2bf(tanh_(h)));
        }
      }
      gsyncf(++step, bar);
    }
  } else {
    // ======================= fc path (shadow GEMM) =========================
    u16 (*Al)[40] = (u16(*)[40])smem;                   // [128][40]
    u16 (*Bl)[40] = (u16(*)[40])(smem + 10240);         // [256][40]

    const int fb = wgid - NBLK;        // 0..124
    const int n0 = fb * 256;

    // convert private fcw slice fp32 -> bf16 (replaces prep_bf16 kernel)
    for (int i = tid; i < 32768; i += 512) {
      const int row = i >> 7;          // 0..255
      const int c8 = (i & 127) * 8;
      const float* s = fcw + (size_t)(n0 + row) * 1024 + c8;
      bf16x8 v = cvt8(*(const float4*)s, *(const float4*)(s + 4));
      *(uint4*)(fcwb + (size_t)(n0 + row) * 1024 + c8) = __builtin_bit_cast(uint4, v);
    }
    __syncthreads();

    const int wm = (wave & 1) * 64;
    const int wn = (wave >> 1) * 64;
    float bj[4];
#pragma unroll
    for (int j = 0; j < 4; ++j) bj[j] = fcb[n0 + wn + j * 16 + fr];

    const int rA = tid >> 2, cA = (tid & 3) * 8;    // A stage: 128r x 32c
    const int rB = tid >> 1, cB = (tid & 1) * 16;   // B stage: 256r x 32c
    const u16* Bs = fcwb + (size_t)(n0 + rB) * 1024 + cB;
    const int mrb = (lane >> 4) * 4;

    for (int m0 = 0; m0 < 16; ++m0) {
      // out2 rows t in [m0*8, m0*8+7] drained once all flags >= m0*8+10
      wait_flags((unsigned)(m0 * 8 + 10), bar);

      f32x4 acc[4][4] = {};
      const u16* Ag = out2b + (size_t)(m0 * 128 + rA) * 1024 + cA;
      for (int k0 = 0; k0 < 1024; k0 += 32) {
        uint4 av;
        ld1_cv(Ag + k0, av);                         // bypass (cross-XCD fresh)
        uint4 b0 = *(const uint4*)(Bs + k0);         // own-converted, own L2
        uint4 b1 = *(const uint4*)(Bs + k0 + 8);
        __syncthreads();
        *(uint4*)&Al[rA][cA] = av;
        *(uint4*)&Bl[rB][cB] = b0;
        *(uint4*)&Bl[rB][cB + 8] = b1;
        __syncthreads();

        bf16x8 af[4], bf[4];
#pragma unroll
        for (int i = 0; i < 4; ++i) af[i] = *(const bf16x8*)&Al[wm + i * 16 + fr][ks8];
#pragma unroll
        for (int j = 0; j < 4; ++j) bf[j] = *(const bf16x8*)&Bl[wn + j * 16 + fr][ks8];
#pragma unroll
        for (int i = 0; i < 4; ++i)
#pragma unroll
          for (int j = 0; j < 4; ++j)
            acc[i][j] = __builtin_amdgcn_mfma_f32_16x16x32_bf16(af[i], bf[j], acc[i][j], 0, 0, 0);
      }

#pragma unroll
      for (int i = 0; i < 4; ++i) {
#pragma unroll
        for (int r = 0; r < 4; ++r) {
          const int m = m0 * 128 + wm + i * 16 + mrb + r;
          float* dst = logits + ((size_t)(m & 15) * 128 + (m >> 4)) * 32000;
#pragma unroll
          for (int j = 0; j < 4; ++j) {
            dst[n0 + wn + j * 16 + fr] = acc[i][j][r] + bj[j];
          }
        }
      }
    }
  }
}

// fallback fc (fp32 B, converts per tile) — used only if ws too small.
__global__ __launch_bounds__(256, 2) void fc_gemm_mfma(
    const u16* __restrict__ A, const float* __restrict__ Bw,
    const float* __restrict__ bias, float* __restrict__ C) {
  __shared__ __align__(16) u16 Al[128][40];
  __shared__ __align__(16) u16 Bl[128][40];
  const int tid = threadIdx.x;
  const int m0 = blockIdx.x * 128;
  const int n0 = blockIdx.y * 128;
  const int wave = tid >> 6;
  const int lane = tid & 63;
  const int wm = (wave & 1) * 64;
  const int wn = (wave >> 1) * 64;
  const int fr = lane & 15;
  const int ks = lane >> 4;
  const int srow = tid >> 1;
  const int sh16 = (tid & 1) * 16;
  const u16* Ag = A + (size_t)(m0 + srow) * 1024 + sh16;
  const float* Bg = Bw + (size_t)(n0 + srow) * 1024 + sh16;
  f32x4 acc[4][4] = {};
  for (int k0 = 0; k0 < 1024; k0 += 32) {
    uint4 a0 = *(const uint4*)(Ag + k0);
    uint4 a1 = *(const uint4*)(Ag + k0 + 8);
    float bfv[16];
    *(float4*)&bfv[0] = *(const float4*)(Bg + k0);
    *(float4*)&bfv[4] = *(const float4*)(Bg + k0 + 4);
    *(float4*)&bfv[8] = *(const float4*)(Bg + k0 + 8);
    *(float4*)&bfv[12] = *(const float4*)(Bg + k0 + 12);
    u16 bu[16];
#pragma unroll
    for (int u = 0; u < 16; ++u) bu[u] = f2bf(bfv[u]);
    __syncthreads();
    *(uint4*)&Al[srow][sh16] = a0;
    *(uint4*)&Al[srow][sh16 + 8] = a1;
    *(uint4*)&Bl[srow][sh16] = *(uint4*)&bu[0];
    *(uint4*)&Bl[srow][sh16 + 8] = *(uint4*)&bu[8];
    __syncthreads();
    bf16x8 af[4], bf[4];
#pragma unroll
    for (int i = 0; i < 4; ++i) af[i] = *(const bf16x8*)&Al[wm + i * 16 + fr][ks * 8];
#pragma unroll
    for (int j = 0; j < 4; ++j) bf[j] = *(const bf16x8*)&Bl[wn + j * 16 + fr][ks * 8];
#pragma unroll
    for (int i = 0; i < 4; ++i)
#pragma unroll
      for (int j = 0; j < 4; ++j)
        acc[i][j] = __builtin_amdgcn_mfma_f32_16x16x32_bf16(af[i], bf[j], acc[i][j], 0, 0, 0);
  }
  float bj[4];
#pragma unroll
  for (int j = 0; j < 4; ++j) bj[j] = bias[n0 + wn + j * 16 + fr];
  const int mrb = (lane >> 4) * 4;
#pragma unroll
  for (int i = 0; i < 4; ++i) {
#pragma unroll
    for (int r = 0; r < 4; ++r) {
      const int m = m0 + wm + i * 16 + mrb + r;
      float* dst = C + ((size_t)(m & 15) * 128 + (m >> 4)) * 32000;
#pragma unroll
      for (int j = 0; j < 4; ++j) dst[n0 + wn + j * 16 + fr] = acc[i][j][r] + bj[j];
    }
  }
}

extern "C" void kernel_launch(void* const* d_in, const int* in_sizes, int n_in,
                              void* d_out, int out_size, void* d_ws, size_t ws_size,
                              hipStream_t stream) {
  const float* enc_h = (const float*)d_in[0];
  const float* enc_c = (const float*)d_in[1];
  const int* tgt = (const int*)d_in[2];
  const float* emb = (const float*)d_in[3];
  const float* wih0 = (const float*)d_in[4];
  const float* whh0 = (const float*)d_in[5];
  const float* bih0 = (const float*)d_in[6];
  const float* bhh0 = (const float*)d_in[7];
  const float* wih1 = (const float*)d_in[8];
  const float* whh1 = (const float*)d_in[9];
  const float* bih1 = (const float*)d_in[10];
  const float* bhh1 = (const float*)d_in[11];
  const float* fcw = (const float*)d_in[12];
  const float* fcb = (const float*)d_in[13];
  float* logits = (float*)d_out;

  unsigned* bar = (unsigned*)d_ws;  // 32 KB barrier region (flags @128B stride)
  hipMemsetAsync(d_ws, 0, 32768, stream);

  // ws layout: bar 32K | cp 256K | x0b 2M | xr 4.125M | h1r 4.125M |
  //            out2b 4M | fcwb 65.5M  (total ~80.6 MB)
  float* cp = (float*)((char*)d_ws + 32768);
  u16* x0b = (u16*)(cp + 65536);
  u16* xr = x0b + 1048576;
  u16* h1r = xr + 2113536;
  u16* out2b = h1r + 2113536;
  u16* fcwb = out2b + 2097152;
  const bool fused = (ws_size >= 80576512ull);

  prep_emb<<<512, 256, 0, stream>>>(tgt, emb, x0b);
  prep_ctx2<<<256, 256, 0, stream>>>(enc_h, wih0, cp);
  if (fused) {
    dec_fc<<<NBLK + NFCB, 512, 0, stream>>>(enc_h, enc_c, wih0, whh0, wih1, whh1,
                                            bih0, bhh0, bih1, bhh1, cp, x0b,
                                            xr, h1r, out2b, fcw, fcb, fcwb,
                                            logits, bar);
  } else {
    dec_fc<<<NBLK, 512, 0, stream>>>(enc_h, enc_c, wih0, whh0, wih1, whh1,
                                     bih0, bhh0, bih1, bhh1, cp, x0b,
                                     xr, h1r, out2b, fcw, fcb, fcwb,
                                     logits, bar);
    fc_gemm_mfma<<<dim3(16, 250), 256, 0, stream>>>(out2b, fcw, fcb, logits);
  }
}

// Round 16
// 974.821 us; speedup vs baseline: 1.4700x; 1.0122x over previous
//
#include <hip/hip_runtime.h>

// Decoder: B=16, T=128, V=32000, E=512, H=1024 (2 LSTM layers), CTX=2048.
// R16: fused dec+fc (R15) with fc A-tile reads switched from per-16B bypass
//   loads (one exposed MALL RTT each; 500MB un-shared traffic; the R15
//   regression) to PLAIN CACHED loads. Safe: fc demand-reads a tile only
//   after the dec flag gate (no pre-gate access -> no stale L2 line; tiles
//   are 256KB-separated), same produce->flag->cached-consume pattern the
//   rings validated in R8-R13. ~16 fc blocks/XCD now share A tiles in L2.
//   - dec path (blocks 0..127): R13 skeleton, register weights, flag barrier.
//   - fc path (blocks 128..252): private 256-row vocab slice, self-converts
//     fcw to bf16, computes 16 (128m x 256n) tiles in t-order in dec's shadow.

#define NBLK 128
#define NFCB 125

typedef float f32x4 __attribute__((ext_vector_type(4)));
typedef __bf16 bf16x8 __attribute__((ext_vector_type(8)));
typedef unsigned short u16;

__device__ __forceinline__ float sigf(float x) { return 1.0f / (1.0f + __expf(-x)); }
__device__ __forceinline__ float tanh_(float x) {
  x = fminf(15.0f, fmaxf(-15.0f, x));
  float e = __expf(2.0f * x);
  return (e - 1.0f) / (e + 1.0f);
}

__device__ __forceinline__ u16 f2bf(float f) {
  __bf16 h = (__bf16)f;  // RNE
  return __builtin_bit_cast(u16, h);
}

__device__ __forceinline__ bf16x8 cvt8(float4 a, float4 b) {
  bf16x8 v;
  v[0] = (__bf16)a.x; v[1] = (__bf16)a.y; v[2] = (__bf16)a.z; v[3] = (__bf16)a.w;
  v[4] = (__bf16)b.x; v[5] = (__bf16)b.y; v[6] = (__bf16)b.z; v[7] = (__bf16)b.w;
  return v;
}

// Coherent (write-through) bf16 store.
__device__ __forceinline__ void st_cv16(u16* p, u16 v) {
  unsigned vv = v;
  asm volatile("global_store_short %0, %1, off sc0 sc1" :: "v"(p), "v"(vv) : "memory");
}

// Plain sc0/sc1 flag store (caller guarantees data already drained).
__device__ __forceinline__ void flag_store(unsigned* p, unsigned v) {
  asm volatile("global_store_dword %0, %1, off sc0 sc1" :: "v"(p), "v"(v) : "memory");
}

// 2 bypass flag loads in flight (no atomic lowering -> no buffer_inv).
__device__ __forceinline__ void ld2_flags(const unsigned* p0, const unsigned* p1,
                                          unsigned& a, unsigned& b) {
  asm volatile(
      "global_load_dword %0, %2, off sc0 sc1\n\t"
      "global_load_dword %1, %3, off sc0 sc1\n\t"
      "s_waitcnt vmcnt(0)"
      : "=&v"(a), "=&v"(b)
      : "v"(p0), "v"(p1)
      : "memory");
}

// Flat one-hop barrier: all threads drain stores, block flag (own 128B line),
// wave0 polls 2 flags/lane.
__device__ __forceinline__ void gsyncf(unsigned step, unsigned* bar) {
  asm volatile("s_waitcnt vmcnt(0)" ::: "memory");
  __syncthreads();
  const int tid = threadIdx.x;
  if (tid == 0) flag_store(bar + 32 + blockIdx.x * 32, step);
  if (tid < 64) {
    const unsigned* p0 = bar + 32 + tid * 64;   // block 2*tid
    const unsigned* p1 = p0 + 32;               // block 2*tid+1
    for (;;) {
      unsigned a, b;
      ld2_flags(p0, p1, a, b);
      if (__all((a >= step) & (b >= step))) break;
      __builtin_amdgcn_s_sleep(1);
    }
    asm volatile("" ::: "memory");
  }
  __syncthreads();
}

// fc-side wait: all 128 dec flags >= target.
__device__ __forceinline__ void wait_flags(unsigned target, const unsigned* bar) {
  const int tid = threadIdx.x;
  if (tid < 64) {
    const unsigned* p0 = bar + 32 + tid * 64;
    const unsigned* p1 = p0 + 32;
    for (;;) {
      unsigned a, b;
      ld2_flags(p0, p1, a, b);
      if (__all((a >= target) & (b >= target))) break;
      __builtin_amdgcn_s_sleep(4);
    }
    asm volatile("" ::: "memory");
  }
  __syncthreads();
}

__device__ __forceinline__ void dot4(float& a, float4 wv, float4 xv) {
  a = fmaf(wv.x, xv.x, a);
  a = fmaf(wv.y, xv.y, a);
  a = fmaf(wv.z, xv.z, a);
  a = fmaf(wv.w, xv.w, a);
}

// ---- prep: gather token embeddings as bf16: x0b[tb][512], tb = t*16+b ----
__global__ void prep_emb(const int* __restrict__ tgt, const float* __restrict__ emb,
                         u16* __restrict__ x0b) {
  const int g = blockIdx.x * blockDim.x + threadIdx.x;  // 131072 total
  const int col8 = (g & 63) * 8;
  const int tb = g >> 6;            // 0..2047
  const int t = tb >> 4, b = tb & 15;
  const int tok = (t == 0) ? 1 : tgt[b * 128 + (t - 1)];
  const float* s = emb + (size_t)tok * 512 + col8;
  float4 a = *(const float4*)s;
  float4 bb = *(const float4*)(s + 4);
  bf16x8 v = cvt8(a, bb);
  *(uint4*)(x0b + (size_t)tb * 512 + col8) = __builtin_bit_cast(uint4, v);
}

// ---- prep: cp[j][b] = sum_k wih0[j][512+k]*ctx[b][k]  (coalesced split-K) --
__global__ __launch_bounds__(256, 1) void prep_ctx2(const float* __restrict__ enc_h,
                                                    const float* __restrict__ wih0,
                                                    float* __restrict__ cp) {
  __shared__ float ctx[16][2052];
  const int tid = threadIdx.x;
#pragma unroll
  for (int c = 0; c < 32; ++c) {
    int f4 = tid + c * 256;
    int b = f4 >> 9, kq = f4 & 511;
    *(float4*)&ctx[b][kq * 4] =
        *(const float4*)(enc_h + (kq >> 7) * 8192 + b * 512 + (kq & 127) * 4);
  }
  __syncthreads();
  const int r = tid >> 4, l = tid & 15;
  const int j = blockIdx.x * 16 + r;
  const float* w = wih0 + (size_t)j * 2560 + 512;
  float acc[16] = {};
#pragma unroll 4
  for (int i = 0; i < 32; ++i) {
    const int k = l * 4 + i * 64;
    const float4 w4 = *(const float4*)(w + k);
#pragma unroll
    for (int b = 0; b < 16; ++b) dot4(acc[b], w4, *(const float4*)&ctx[b][k]);
  }
#pragma unroll
  for (int off = 1; off < 16; off <<= 1)
#pragma unroll
    for (int b = 0; b < 16; ++b) acc[b] += __shfl_xor(acc[b], off);
  cp[(size_t)j * 16 + l] = acc[l];
}

// 16 chained MFMAs; A-frags from LDS slab BP (stride S u16, col off XOFF),
// B-frags from register weights BW[16].
#define BURST(ACC, BP, S, XOFF, BW)                                            \
  _Pragma("unroll")                                                            \
  for (int mm = 0; mm < 16; ++mm) {                                            \
    bf16x8 av = *(const bf16x8*)&(BP)[fr * (S) + (XOFF) + mm * 32 + ks8];      \
    ACC = __builtin_amdgcn_mfma_f32_16x16x32_bf16(av, (BW)[mm], ACC, 0, 0, 0); \
  }

// Load one burst's 16 weight fragments into registers.
__device__ __forceinline__ void loadw(bf16x8* dst, int q, int w8, int lane,
                                      const float* wih0, const float* whh0,
                                      const float* wih1, const float* whh1) {
  const int c = q >> 1, tile = q & 1;
  const int nn = lane & 15;
  const int gate = tile * 2 + (nn >> 3);
  const int unit = nn & 7;
  const int j = gate * 1024 + w8 + unit;
  const float* src;
  size_t stride = 1024;
  int ko = 0;
  if (c == 0) { src = wih0; stride = 2560; ko = 0; }
  else if (c <= 2) { src = whh0; ko = (c - 1) * 512; }
  else if (c <= 4) { src = wih1; ko = (c - 3) * 512; }
  else { src = whh1; ko = (c - 5) * 512; }
  const float* base = src + (size_t)j * stride + ko + ((lane >> 4) * 8);
#pragma unroll
  for (int mm = 0; mm < 16; ++mm) {
    const float* sp = base + mm * 32;
    dst[mm] = cvt8(*(const float4*)sp, *(const float4*)(sp + 4));
  }
}

// ---------------- FUSED persistent decoder + shadow logits GEMM -----------
__global__ __launch_bounds__(512, 1) void dec_fc(
    const float* __restrict__ enc_h, const float* __restrict__ enc_c,
    const float* __restrict__ wih0, const float* __restrict__ whh0,
    const float* __restrict__ wih1, const float* __restrict__ whh1,
    const float* __restrict__ bih0, const float* __restrict__ bhh0,
    const float* __restrict__ bih1, const float* __restrict__ bhh1,
    const float* __restrict__ cp, const u16* __restrict__ x0b,
    u16* __restrict__ xr, u16* __restrict__ h1r, u16* __restrict__ out2b,
    const float* __restrict__ fcw, const float* __restrict__ fcb,
    u16* __restrict__ fcwb, float* __restrict__ logits, unsigned* bar) {
  // overlaid shared memory: dec uses 97920B; fc uses 30720B
  __shared__ __align__(16) char smem[97920];

  const int tid = threadIdx.x;
  const int wgid = blockIdx.x;
  const int lane = tid & 63;
  const int wave = tid >> 6;
  const int fr = lane & 15;
  const int ks8 = (lane >> 4) * 8;

  if (wgid < NBLK) {
    // ======================= dec path (R13 skeleton) =======================
    u16* xe = (u16*)smem;                       // 16*520
    u16* xs = xe + 16 * 520;                    // 16*1032
    u16* h1s = xs + 16 * 1032;                  // 16*1032
    float (*gls)[16][17] = (float(*)[16][17])(h1s + 16 * 1032);  // [14][16][17]

    const int w8 = wgid * 8;
    unsigned step = 0;

    bf16x8 bw0[16], bw1[16];
    const int q0 = (wave < 6) ? 2 * wave : (wave == 6 ? 12 : 13);
    loadw(bw0, q0, w8, lane, wih0, whh0, wih1, whh1);
    if (wave < 6) loadw(bw1, 2 * wave + 1, w8, lane, wih0, whh0, wih1, whh1);
    else {
#pragma unroll
      for (int mm = 0; mm < 16; ++mm) bw1[mm] = bf16x8{};
    }

    const int gdj = (tid >> 4) & 7;
    const int gb = tid & 15;
    float cpA0 = 0.f, cpA1 = 0.f, cpA2 = 0.f, cpA3 = 0.f;
    float cpB0 = 0.f, cpB1 = 0.f, cpB2 = 0.f, cpB3 = 0.f;
    float c0r = 0.f, c1r = 0.f;
    if (tid < 128) {
      const int jp = w8 + gdj;
      cpA0 = cp[(size_t)(jp) * 16 + gb] + bih0[jp] + bhh0[jp];
      cpA1 = cp[(size_t)(1024 + jp) * 16 + gb] + bih0[1024 + jp] + bhh0[1024 + jp];
      cpA2 = cp[(size_t)(2048 + jp) * 16 + gb] + bih0[2048 + jp] + bhh0[2048 + jp];
      cpA3 = cp[(size_t)(3072 + jp) * 16 + gb] + bih0[3072 + jp] + bhh0[3072 + jp];
      cpB0 = bih1[jp] + bhh1[jp];
      cpB1 = bih1[1024 + jp] + bhh1[1024 + jp];
      cpB2 = bih1[2048 + jp] + bhh1[2048 + jp];
      cpB3 = bih1[3072 + jp] + bhh1[3072 + jp];
      const int dir = jp >> 9, e = jp & 511;
      c0r = enc_c[dir * 8192 + gb * 512 + e];
      c1r = enc_c[(2 + dir) * 8192 + gb * 512 + e];
      st_cv16(xr + gb * 1024 + jp, f2bf(enc_h[dir * 8192 + gb * 512 + e]));
      st_cv16(h1r + gb * 1024 + jp, f2bf(enc_h[(2 + dir) * 8192 + gb * 512 + e]));
    }

    const int sm = tid >> 5;
    const int skq = (tid & 31) * 8;

    {
      const u16* se = x0b + sm * 512;
#pragma unroll
      for (int jj = 0; jj < 2; ++jj)
        *(uint4*)&xe[sm * 520 + skq + jj * 256] = *(const uint4*)(se + skq + jj * 256);
    }
    gsyncf(++step, bar);

    for (int s = 0; s < 129; ++s) {
      const bool doA = (s < 128), doB = (s >= 1);

      uint4 rx[4], rh[4] = {}, re[2] = {};
      {
        const u16* sx = xr + (size_t)s * 16384 + sm * 1024;
#pragma unroll
        for (int jj = 0; jj < 4; ++jj) rx[jj] = *(const uint4*)(sx + skq + jj * 256);
        if (doB) {
          const u16* sh = h1r + (size_t)(s - 1) * 16384 + sm * 1024;
#pragma unroll
          for (int jj = 0; jj < 4; ++jj) rh[jj] = *(const uint4*)(sh + skq + jj * 256);
        }
        if (s < 127) {
          const u16* se = x0b + (size_t)(s + 1) * 8192 + sm * 512;
#pragma unroll
          for (int jj = 0; jj < 2; ++jj) re[jj] = *(const uint4*)(se + skq + jj * 256);
        }
      }
#pragma unroll
      for (int jj = 0; jj < 4; ++jj) *(uint4*)&xs[sm * 1032 + skq + jj * 256] = rx[jj];
      if (doB) {
#pragma unroll
        for (int jj = 0; jj < 4; ++jj) *(uint4*)&h1s[sm * 1032 + skq + jj * 256] = rh[jj];
      }
      __syncthreads();

      f32x4 acc0 = {0.f, 0.f, 0.f, 0.f}, acc1 = {0.f, 0.f, 0.f, 0.f};
      bool act0 = false, act1 = false;
      if (wave == 0) { if (doA) { BURST(acc0, xe, 520, 0, bw0) BURST(acc1, xe, 520, 0, bw1) act0 = act1 = true; } }
      else if (wave == 1) { if (doA) { BURST(acc0, xs, 1032, 0, bw0) BURST(acc1, xs, 1032, 0, bw1) act0 = act1 = true; } }
      else if (wave == 2) { if (doA) { BURST(acc0, xs, 1032, 512, bw0) BURST(acc1, xs, 1032, 512, bw1) act0 = act1 = true; } }
      else if (wave == 3) { if (doB) { BURST(acc0, xs, 1032, 0, bw0) BURST(acc1, xs, 1032, 0, bw1) act0 = act1 = true; } }
      else if (wave == 4) { if (doB) { BURST(acc0, xs, 1032, 512, bw0) BURST(acc1, xs, 1032, 512, bw1) act0 = act1 = true; } }
      else if (wave == 5) { if (doB) { BURST(acc0, h1s, 1032, 0, bw0) BURST(acc1, h1s, 1032, 0, bw1) act0 = act1 = true; } }
      else if (wave == 6) { if (doB) { BURST(acc0, h1s, 1032, 512, bw0) act0 = true; } }
      else { if (doB) { BURST(acc0, h1s, 1032, 512, bw0) act0 = true; } }
      if (act0) {
#pragma unroll
        for (int r = 0; r < 4; ++r) gls[q0][fr][(lane >> 4) * 4 + r] = acc0[r];
      }
      if (act1) {
#pragma unroll
        for (int r = 0; r < 4; ++r) gls[q0 + 1][fr][(lane >> 4) * 4 + r] = acc1[r];
      }
      __syncthreads();

      if (s < 127) {
#pragma unroll
        for (int jj = 0; jj < 2; ++jj) *(uint4*)&xe[sm * 520 + skq + jj * 256] = re[jj];
      }

      if (tid < 128) {
        const int jp = w8 + gdj;
        if (doA) {
          float gi = gls[0][gdj][gb] + gls[2][gdj][gb] + gls[4][gdj][gb] + cpA0;
          float gf = gls[0][8 + gdj][gb] + gls[2][8 + gdj][gb] + gls[4][8 + gdj][gb] + cpA1;
          float gg = gls[1][gdj][gb] + gls[3][gdj][gb] + gls[5][gdj][gb] + cpA2;
          float go = gls[1][8 + gdj][gb] + gls[3][8 + gdj][gb] + gls[5][8 + gdj][gb] + cpA3;
          c0r = sigf(gf) * c0r + sigf(gi) * tanh_(gg);
          float h = sigf(go) * tanh_(c0r);
          st_cv16(xr + (size_t)(s + 1) * 16384 + gb * 1024 + jp, f2bf(h));
        }
        if (doB) {
          float gi = gls[6][gdj][gb] + gls[8][gdj][gb] + gls[10][gdj][gb] +
                     gls[12][gdj][gb] + cpB0;
          float gf = gls[6][8 + gdj][gb] + gls[8][8 + gdj][gb] + gls[10][8 + gdj][gb] +
                     gls[12][8 + gdj][gb] + cpB1;
          float gg = gls[7][gdj][gb] + gls[9][gdj][gb] + gls[11][gdj][gb] +
                     gls[13][gdj][gb] + cpB2;
          float go = gls[7][8 + gdj][gb] + gls[9][8 + gdj][gb] + gls[11][8 + gdj][gb] +
                     gls[13][8 + gdj][gb] + cpB3;
          c1r = sigf(gf) * c1r + sigf(gi) * tanh_(gg);
          float h = sigf(go) * tanh_(c1r);
          st_cv16(h1r + (size_t)s * 16384 + gb * 1024 + jp, f2bf(h));
          // WRITE-THROUGH: fc blocks on other XCDs consume within this kernel
          st_cv16(out2b + ((s - 1) * 16 + gb) * 1024 + jp, f2bf(tanh_(h)));
        }
      }
      gsyncf(++step, bar);
    }
  } else {
    // ======================= fc path (shadow GEMM) =========================
    u16 (*Al)[40] = (u16(*)[40])smem;                   // [128][40]
    u16 (*Bl)[40] = (u16(*)[40])(smem + 10240);         // [256][40]

    const int fb = wgid - NBLK;        // 0..124
    const int n0 = fb * 256;

    // convert private fcw slice fp32 -> bf16 (replaces prep_bf16 kernel)
    for (int i = tid; i < 32768; i += 512) {
      const int row = i >> 7;          // 0..255
      const int c8 = (i & 127) * 8;
      const float* s = fcw + (size_t)(n0 + row) * 1024 + c8;
      bf16x8 v = cvt8(*(const float4*)s, *(const float4*)(s + 4));
      *(uint4*)(fcwb + (size_t)(n0 + row) * 1024 + c8) = __builtin_bit_cast(uint4, v);
    }
    __syncthreads();

    const int wm = (wave & 1) * 64;
    const int wn = (wave >> 1) * 64;
    float bj[4];
#pragma unroll
    for (int j = 0; j < 4; ++j) bj[j] = fcb[n0 + wn + j * 16 + fr];

    const int rA = tid >> 2, cA = (tid & 3) * 8;    // A stage: 128r x 32c
    const int rB = tid >> 1, cB = (tid & 1) * 16;   // B stage: 256r x 32c
    const u16* Bs = fcwb + (size_t)(n0 + rB) * 1024 + cB;
    const int mrb = (lane >> 4) * 4;

    for (int m0 = 0; m0 < 16; ++m0) {
      // out2 rows t in [m0*8, m0*8+7] drained once all flags >= m0*8+10.
      // After the gate, PLAIN CACHED reads are safe (demand-only access:
      // these addresses were never touched before the gate) and ~16 fc
      // blocks/XCD share the tile in L2 (R15's bypass = 500MB un-shared).
      wait_flags((unsigned)(m0 * 8 + 10), bar);

      f32x4 acc[4][4] = {};
      const u16* Ag = out2b + (size_t)(m0 * 128 + rA) * 1024 + cA;
      for (int k0 = 0; k0 < 1024; k0 += 32) {
        uint4 av = *(const uint4*)(Ag + k0);         // plain cached (gated)
        uint4 b0 = *(const uint4*)(Bs + k0);         // own-converted, own L2
        uint4 b1 = *(const uint4*)(Bs + k0 + 8);
        __syncthreads();
        *(uint4*)&Al[rA][cA] = av;
        *(uint4*)&Bl[rB][cB] = b0;
        *(uint4*)&Bl[rB][cB + 8] = b1;
        __syncthreads();

        bf16x8 af[4], bf[4];
#pragma unroll
        for (int i = 0; i < 4; ++i) af[i] = *(const bf16x8*)&Al[wm + i * 16 + fr][ks8];
#pragma unroll
        for (int j = 0; j < 4; ++j) bf[j] = *(const bf16x8*)&Bl[wn + j * 16 + fr][ks8];
#pragma unroll
        for (int i = 0; i < 4; ++i)
#pragma unroll
          for (int j = 0; j < 4; ++j)
            acc[i][j] = __builtin_amdgcn_mfma_f32_16x16x32_bf16(af[i], bf[j], acc[i][j], 0, 0, 0);
      }

#pragma unroll
      for (int i = 0; i < 4; ++i) {
#pragma unroll
        for (int r = 0; r < 4; ++r) {
          const int m = m0 * 128 + wm + i * 16 + mrb + r;
          float* dst = logits + ((size_t)(m & 15) * 128 + (m >> 4)) * 32000;
#pragma unroll
          for (int j = 0; j < 4; ++j) {
            dst[n0 + wn + j * 16 + fr] = acc[i][j][r] + bj[j];
          }
        }
      }
    }
  }
}

// fallback fc (fp32 B, converts per tile) — used only if ws too small.
__global__ __launch_bounds__(256, 2) void fc_gemm_mfma(
    const u16* __restrict__ A, const float* __restrict__ Bw,
    const float* __restrict__ bias, float* __restrict__ C) {
  __shared__ __align__(16) u16 Al[128][40];
  __shared__ __align__(16) u16 Bl[128][40];
  const int tid = threadIdx.x;
  const int m0 = blockIdx.x * 128;
  const int n0 = blockIdx.y * 128;
  const int wave = tid >> 6;
  const int lane = tid & 63;
  const int wm = (wave & 1) * 64;
  const int wn = (wave >> 1) * 64;
  const int fr = lane & 15;
  const int ks = lane >> 4;
  const int srow = tid >> 1;
  const int sh16 = (tid & 1) * 16;
  const u16* Ag = A + (size_t)(m0 + srow) * 1024 + sh16;
  const float* Bg = Bw + (size_t)(n0 + srow) * 1024 + sh16;
  f32x4 acc[4][4] = {};
  for (int k0 = 0; k0 < 1024; k0 += 32) {
    uint4 a0 = *(const uint4*)(Ag + k0);
    uint4 a1 = *(const uint4*)(Ag + k0 + 8);
    float bfv[16];
    *(float4*)&bfv[0] = *(const float4*)(Bg + k0);
    *(float4*)&bfv[4] = *(const float4*)(Bg + k0 + 4);
    *(float4*)&bfv[8] = *(const float4*)(Bg + k0 + 8);
    *(float4*)&bfv[12] = *(const float4*)(Bg + k0 + 12);
    u16 bu[16];
#pragma unroll
    for (int u = 0; u < 16; ++u) bu[u] = f2bf(bfv[u]);
    __syncthreads();
    *(uint4*)&Al[srow][sh16] = a0;
    *(uint4*)&Al[srow][sh16 + 8] = a1;
    *(uint4*)&Bl[srow][sh16] = *(uint4*)&bu[0];
    *(uint4*)&Bl[srow][sh16 + 8] = *(uint4*)&bu[8];
    __syncthreads();
    bf16x8 af[4], bf[4];
#pragma unroll
    for (int i = 0; i < 4; ++i) af[i] = *(const bf16x8*)&Al[wm + i * 16 + fr][ks * 8];
#pragma unroll
    for (int j = 0; j < 4; ++j) bf[j] = *(const bf16x8*)&Bl[wn + j * 16 + fr][ks * 8];
#pragma unroll
    for (int i = 0; i < 4; ++i)
#pragma unroll
      for (int j = 0; j < 4; ++j)
        acc[i][j] = __builtin_amdgcn_mfma_f32_16x16x32_bf16(af[i], bf[j], acc[i][j], 0, 0, 0);
  }
  float bj[4];
#pragma unroll
  for (int j = 0; j < 4; ++j) bj[j] = bias[n0 + wn + j * 16 + fr];
  const int mrb = (lane >> 4) * 4;
#pragma unroll
  for (int i = 0; i < 4; ++i) {
#pragma unroll
    for (int r = 0; r < 4; ++r) {
      const int m = m0 + wm + i * 16 + mrb + r;
      float* dst = C + ((size_t)(m & 15) * 128 + (m >> 4)) * 32000;
#pragma unroll
      for (int j = 0; j < 4; ++j) dst[n0 + wn + j * 16 + fr] = acc[i][j][r] + bj[j];
    }
  }
}

extern "C" void kernel_launch(void* const* d_in, const int* in_sizes, int n_in,
                              void* d_out, int out_size, void* d_ws, size_t ws_size,
                              hipStream_t stream) {
  const float* enc_h = (const float*)d_in[0];
  const float* enc_c = (const float*)d_in[1];
  const int* tgt = (const int*)d_in[2];
  const float* emb = (const float*)d_in[3];
  const float* wih0 = (const float*)d_in[4];
  const float* whh0 = (const float*)d_in[5];
  const float* bih0 = (const float*)d_in[6];
  const float* bhh0 = (const float*)d_in[7];
  const float* wih1 = (const float*)d_in[8];
  const float* whh1 = (const float*)d_in[9];
  const float* bih1 = (const float*)d_in[10];
  const float* bhh1 = (const float*)d_in[11];
  const float* fcw = (const float*)d_in[12];
  const float* fcb = (const float*)d_in[13];
  float* logits = (float*)d_out;

  unsigned* bar = (unsigned*)d_ws;  // 32 KB barrier region (flags @128B stride)
  hipMemsetAsync(d_ws, 0, 32768, stream);

  // ws layout: bar 32K | cp 256K | x0b 2M | xr 4.125M | h1r 4.125M |
  //            out2b 4M | fcwb 65.5M  (total ~80.6 MB)
  float* cp = (float*)((char*)d_ws + 32768);
  u16* x0b = (u16*)(cp + 65536);
  u16* xr = x0b + 1048576;
  u16* h1r = xr + 2113536;
  u16* out2b = h1r + 2113536;
  u16* fcwb = out2b + 2097152;
  const bool fused = (ws_size >= 80576512ull);

  prep_emb<<<512, 256, 0, stream>>>(tgt, emb, x0b);
  prep_ctx2<<<256, 256, 0, stream>>>(enc_h, wih0, cp);
  if (fused) {
    dec_fc<<<NBLK + NFCB, 512, 0, stream>>>(enc_h, enc_c, wih0, whh0, wih1, whh1,
                                            bih0, bhh0, bih1, bhh1, cp, x0b,
                                            xr, h1r, out2b, fcw, fcb, fcwb,
                                            logits, bar);
  } else {
    dec_fc<<<NBLK, 512, 0, stream>>>(enc_h, enc_c, wih0, whh0, wih1, whh1,
                                     bih0, bhh0, bih1, bhh1, cp, x0b,
                                     xr, h1r, out2b, fcw, fcb, fcwb,
                                     logits, bar);
    fc_gemm_mfma<<<dim3(16, 250), 256, 0, stream>>>(out2b, fcw, fcb, logits);
  }
}

// Round 17
// 964.934 us; speedup vs baseline: 1.4851x; 1.0102x over previous
//
#include <hip/hip_runtime.h>

// Decoder: B=16, T=128, V=32000, E=512, H=1024 (2 LSTM layers), CTX=2048.
// R17: fused dec+fc with AGGREGATED gate flag.
//   R16 left dec cadence degraded (7.5 vs 5.7us/step): 125 fc blocks each
//   re-reading 128 flag dwords every ~1us (~55GB/s on the barrier's own
//   lines) queued dec's observe hop. Now dec block 0 publishes its barrier
//   poll result ("all flags >= step") to bar[0]; fc blocks poll that ONE
//   dword with s_sleep(32). Flag-line traffic drops ~4000x.
//   - dec path (blocks 0..127): R13 skeleton, register weights, flag barrier.
//   - fc path (blocks 128..252): private 256-row vocab slice, self-converts
//     fcw to bf16, 16 (128m x 256n) tiles in t-order in dec's shadow;
//     A-tiles plain cached after the gate (R16).

#define NBLK 128
#define NFCB 125

typedef float f32x4 __attribute__((ext_vector_type(4)));
typedef __bf16 bf16x8 __attribute__((ext_vector_type(8)));
typedef unsigned short u16;

__device__ __forceinline__ float sigf(float x) { return 1.0f / (1.0f + __expf(-x)); }
__device__ __forceinline__ float tanh_(float x) {
  x = fminf(15.0f, fmaxf(-15.0f, x));
  float e = __expf(2.0f * x);
  return (e - 1.0f) / (e + 1.0f);
}

__device__ __forceinline__ u16 f2bf(float f) {
  __bf16 h = (__bf16)f;  // RNE
  return __builtin_bit_cast(u16, h);
}

__device__ __forceinline__ bf16x8 cvt8(float4 a, float4 b) {
  bf16x8 v;
  v[0] = (__bf16)a.x; v[1] = (__bf16)a.y; v[2] = (__bf16)a.z; v[3] = (__bf16)a.w;
  v[4] = (__bf16)b.x; v[5] = (__bf16)b.y; v[6] = (__bf16)b.z; v[7] = (__bf16)b.w;
  return v;
}

// Coherent (write-through) bf16 store.
__device__ __forceinline__ void st_cv16(u16* p, u16 v) {
  unsigned vv = v;
  asm volatile("global_store_short %0, %1, off sc0 sc1" :: "v"(p), "v"(vv) : "memory");
}

// Plain sc0/sc1 flag store (caller guarantees data already drained).
__device__ __forceinline__ void flag_store(unsigned* p, unsigned v) {
  asm volatile("global_store_dword %0, %1, off sc0 sc1" :: "v"(p), "v"(v) : "memory");
}

// 2 bypass flag loads in flight (no atomic lowering -> no buffer_inv).
__device__ __forceinline__ void ld2_flags(const unsigned* p0, const unsigned* p1,
                                          unsigned& a, unsigned& b) {
  asm volatile(
      "global_load_dword %0, %2, off sc0 sc1\n\t"
      "global_load_dword %1, %3, off sc0 sc1\n\t"
      "s_waitcnt vmcnt(0)"
      : "=&v"(a), "=&v"(b)
      : "v"(p0), "v"(p1)
      : "memory");
}

// Single bypass flag load.
__device__ __forceinline__ unsigned ld1_flag(const unsigned* p) {
  unsigned a;
  asm volatile(
      "global_load_dword %0, %1, off sc0 sc1\n\t"
      "s_waitcnt vmcnt(0)"
      : "=&v"(a) : "v"(p) : "memory");
  return a;
}

// Flat one-hop barrier. Block 0 additionally publishes the aggregated step
// to bar[0] after its poll succeeds (fc blocks gate on that single word).
__device__ __forceinline__ void gsyncf(unsigned step, unsigned* bar) {
  asm volatile("s_waitcnt vmcnt(0)" ::: "memory");
  __syncthreads();
  const int tid = threadIdx.x;
  if (tid == 0) flag_store(bar + 32 + blockIdx.x * 32, step);
  if (tid < 64) {
    const unsigned* p0 = bar + 32 + tid * 64;   // block 2*tid
    const unsigned* p1 = p0 + 32;               // block 2*tid+1
    for (;;) {
      unsigned a, b;
      ld2_flags(p0, p1, a, b);
      if (__all((a >= step) & (b >= step))) break;
      __builtin_amdgcn_s_sleep(1);
    }
    asm volatile("" ::: "memory");
    if (blockIdx.x == 0 && tid == 0) flag_store(bar, step);  // aggregated gate
  }
  __syncthreads();
}

// fc-side gate: poll the single aggregated word (trivial traffic).
__device__ __forceinline__ void wait_agg(unsigned target, const unsigned* bar) {
  if (threadIdx.x == 0) {
    while (ld1_flag(bar) < target) __builtin_amdgcn_s_sleep(32);
    asm volatile("" ::: "memory");
  }
  __syncthreads();
}

__device__ __forceinline__ void dot4(float& a, float4 wv, float4 xv) {
  a = fmaf(wv.x, xv.x, a);
  a = fmaf(wv.y, xv.y, a);
  a = fmaf(wv.z, xv.z, a);
  a = fmaf(wv.w, xv.w, a);
}

// ---- prep: gather token embeddings as bf16: x0b[tb][512], tb = t*16+b ----
__global__ void prep_emb(const int* __restrict__ tgt, const float* __restrict__ emb,
                         u16* __restrict__ x0b) {
  const int g = blockIdx.x * blockDim.x + threadIdx.x;  // 131072 total
  const int col8 = (g & 63) * 8;
  const int tb = g >> 6;            // 0..2047
  const int t = tb >> 4, b = tb & 15;
  const int tok = (t == 0) ? 1 : tgt[b * 128 + (t - 1)];
  const float* s = emb + (size_t)tok * 512 + col8;
  float4 a = *(const float4*)s;
  float4 bb = *(const float4*)(s + 4);
  bf16x8 v = cvt8(a, bb);
  *(uint4*)(x0b + (size_t)tb * 512 + col8) = __builtin_bit_cast(uint4, v);
}

// ---- prep: cp[j][b] = sum_k wih0[j][512+k]*ctx[b][k]  (coalesced split-K) --
__global__ __launch_bounds__(256, 1) void prep_ctx2(const float* __restrict__ enc_h,
                                                    const float* __restrict__ wih0,
                                                    float* __restrict__ cp) {
  __shared__ float ctx[16][2052];
  const int tid = threadIdx.x;
#pragma unroll
  for (int c = 0; c < 32; ++c) {
    int f4 = tid + c * 256;
    int b = f4 >> 9, kq = f4 & 511;
    *(float4*)&ctx[b][kq * 4] =
        *(const float4*)(enc_h + (kq >> 7) * 8192 + b * 512 + (kq & 127) * 4);
  }
  __syncthreads();
  const int r = tid >> 4, l = tid & 15;
  const int j = blockIdx.x * 16 + r;
  const float* w = wih0 + (size_t)j * 2560 + 512;
  float acc[16] = {};
#pragma unroll 4
  for (int i = 0; i < 32; ++i) {
    const int k = l * 4 + i * 64;
    const float4 w4 = *(const float4*)(w + k);
#pragma unroll
    for (int b = 0; b < 16; ++b) dot4(acc[b], w4, *(const float4*)&ctx[b][k]);
  }
#pragma unroll
  for (int off = 1; off < 16; off <<= 1)
#pragma unroll
    for (int b = 0; b < 16; ++b) acc[b] += __shfl_xor(acc[b], off);
  cp[(size_t)j * 16 + l] = acc[l];
}

// 16 chained MFMAs; A-frags from LDS slab BP (stride S u16, col off XOFF),
// B-frags from register weights BW[16].
#define BURST(ACC, BP, S, XOFF, BW)                                            \
  _Pragma("unroll")                                                            \
  for (int mm = 0; mm < 16; ++mm) {                                            \
    bf16x8 av = *(const bf16x8*)&(BP)[fr * (S) + (XOFF) + mm * 32 + ks8];      \
    ACC = __builtin_amdgcn_mfma_f32_16x16x32_bf16(av, (BW)[mm], ACC, 0, 0, 0); \
  }

// Load one burst's 16 weight fragments into registers.
__device__ __forceinline__ void loadw(bf16x8* dst, int q, int w8, int lane,
                                      const float* wih0, const float* whh0,
                                      const float* wih1, const float* whh1) {
  const int c = q >> 1, tile = q & 1;
  const int nn = lane & 15;
  const int gate = tile * 2 + (nn >> 3);
  const int unit = nn & 7;
  const int j = gate * 1024 + w8 + unit;
  const float* src;
  size_t stride = 1024;
  int ko = 0;
  if (c == 0) { src = wih0; stride = 2560; ko = 0; }
  else if (c <= 2) { src = whh0; ko = (c - 1) * 512; }
  else if (c <= 4) { src = wih1; ko = (c - 3) * 512; }
  else { src = whh1; ko = (c - 5) * 512; }
  const float* base = src + (size_t)j * stride + ko + ((lane >> 4) * 8);
#pragma unroll
  for (int mm = 0; mm < 16; ++mm) {
    const float* sp = base + mm * 32;
    dst[mm] = cvt8(*(const float4*)sp, *(const float4*)(sp + 4));
  }
}

// ---------------- FUSED persistent decoder + shadow logits GEMM -----------
__global__ __launch_bounds__(512, 1) void dec_fc(
    const float* __restrict__ enc_h, const float* __restrict__ enc_c,
    const float* __restrict__ wih0, const float* __restrict__ whh0,
    const float* __restrict__ wih1, const float* __restrict__ whh1,
    const float* __restrict__ bih0, const float* __restrict__ bhh0,
    const float* __restrict__ bih1, const float* __restrict__ bhh1,
    const float* __restrict__ cp, const u16* __restrict__ x0b,
    u16* __restrict__ xr, u16* __restrict__ h1r, u16* __restrict__ out2b,
    const float* __restrict__ fcw, const float* __restrict__ fcb,
    u16* __restrict__ fcwb, float* __restrict__ logits, unsigned* bar) {
  // overlaid shared memory: dec uses 97920B; fc uses 30720B
  __shared__ __align__(16) char smem[97920];

  const int tid = threadIdx.x;
  const int wgid = blockIdx.x;
  const int lane = tid & 63;
  const int wave = tid >> 6;
  const int fr = lane & 15;
  const int ks8 = (lane >> 4) * 8;

  if (wgid < NBLK) {
    // ======================= dec path (R13 skeleton) =======================
    u16* xe = (u16*)smem;                       // 16*520
    u16* xs = xe + 16 * 520;                    // 16*1032
    u16* h1s = xs + 16 * 1032;                  // 16*1032
    float (*gls)[16][17] = (float(*)[16][17])(h1s + 16 * 1032);  // [14][16][17]

    const int w8 = wgid * 8;
    unsigned step = 0;

    bf16x8 bw0[16], bw1[16];
    const int q0 = (wave < 6) ? 2 * wave : (wave == 6 ? 12 : 13);
    loadw(bw0, q0, w8, lane, wih0, whh0, wih1, whh1);
    if (wave < 6) loadw(bw1, 2 * wave + 1, w8, lane, wih0, whh0, wih1, whh1);
    else {
#pragma unroll
      for (int mm = 0; mm < 16; ++mm) bw1[mm] = bf16x8{};
    }

    const int gdj = (tid >> 4) & 7;
    const int gb = tid & 15;
    float cpA0 = 0.f, cpA1 = 0.f, cpA2 = 0.f, cpA3 = 0.f;
    float cpB0 = 0.f, cpB1 = 0.f, cpB2 = 0.f, cpB3 = 0.f;
    float c0r = 0.f, c1r = 0.f;
    if (tid < 128) {
      const int jp = w8 + gdj;
      cpA0 = cp[(size_t)(jp) * 16 + gb] + bih0[jp] + bhh0[jp];
      cpA1 = cp[(size_t)(1024 + jp) * 16 + gb] + bih0[1024 + jp] + bhh0[1024 + jp];
      cpA2 = cp[(size_t)(2048 + jp) * 16 + gb] + bih0[2048 + jp] + bhh0[2048 + jp];
      cpA3 = cp[(size_t)(3072 + jp) * 16 + gb] + bih0[3072 + jp] + bhh0[3072 + jp];
      cpB0 = bih1[jp] + bhh1[jp];
      cpB1 = bih1[1024 + jp] + bhh1[1024 + jp];
      cpB2 = bih1[2048 + jp] + bhh1[2048 + jp];
      cpB3 = bih1[3072 + jp] + bhh1[3072 + jp];
      const int dir = jp >> 9, e = jp & 511;
      c0r = enc_c[dir * 8192 + gb * 512 + e];
      c1r = enc_c[(2 + dir) * 8192 + gb * 512 + e];
      st_cv16(xr + gb * 1024 + jp, f2bf(enc_h[dir * 8192 + gb * 512 + e]));
      st_cv16(h1r + gb * 1024 + jp, f2bf(enc_h[(2 + dir) * 8192 + gb * 512 + e]));
    }

    const int sm = tid >> 5;
    const int skq = (tid & 31) * 8;

    {
      const u16* se = x0b + sm * 512;
#pragma unroll
      for (int jj = 0; jj < 2; ++jj)
        *(uint4*)&xe[sm * 520 + skq + jj * 256] = *(const uint4*)(se + skq + jj * 256);
    }
    gsyncf(++step, bar);

    for (int s = 0; s < 129; ++s) {
      const bool doA = (s < 128), doB = (s >= 1);

      uint4 rx[4], rh[4] = {}, re[2] = {};
      {
        const u16* sx = xr + (size_t)s * 16384 + sm * 1024;
#pragma unroll
        for (int jj = 0; jj < 4; ++jj) rx[jj] = *(const uint4*)(sx + skq + jj * 256);
        if (doB) {
          const u16* sh = h1r + (size_t)(s - 1) * 16384 + sm * 1024;
#pragma unroll
          for (int jj = 0; jj < 4; ++jj) rh[jj] = *(const uint4*)(sh + skq + jj * 256);
        }
        if (s < 127) {
          const u16* se = x0b + (size_t)(s + 1) * 8192 + sm * 512;
#pragma unroll
          for (int jj = 0; jj < 2; ++jj) re[jj] = *(const uint4*)(se + skq + jj * 256);
        }
      }
#pragma unroll
      for (int jj = 0; jj < 4; ++jj) *(uint4*)&xs[sm * 1032 + skq + jj * 256] = rx[jj];
      if (doB) {
#pragma unroll
        for (int jj = 0; jj < 4; ++jj) *(uint4*)&h1s[sm * 1032 + skq + jj * 256] = rh[jj];
      }
      __syncthreads();

      f32x4 acc0 = {0.f, 0.f, 0.f, 0.f}, acc1 = {0.f, 0.f, 0.f, 0.f};
      bool act0 = false, act1 = false;
      if (wave == 0) { if (doA) { BURST(acc0, xe, 520, 0, bw0) BURST(acc1, xe, 520, 0, bw1) act0 = act1 = true; } }
      else if (wave == 1) { if (doA) { BURST(acc0, xs, 1032, 0, bw0) BURST(acc1, xs, 1032, 0, bw1) act0 = act1 = true; } }
      else if (wave == 2) { if (doA) { BURST(acc0, xs, 1032, 512, bw0) BURST(acc1, xs, 1032, 512, bw1) act0 = act1 = true; } }
      else if (wave == 3) { if (doB) { BURST(acc0, xs, 1032, 0, bw0) BURST(acc1, xs, 1032, 0, bw1) act0 = act1 = true; } }
      else if (wave == 4) { if (doB) { BURST(acc0, xs, 1032, 512, bw0) BURST(acc1, xs, 1032, 512, bw1) act0 = act1 = true; } }
      else if (wave == 5) { if (doB) { BURST(acc0, h1s, 1032, 0, bw0) BURST(acc1, h1s, 1032, 0, bw1) act0 = act1 = true; } }
      else if (wave == 6) { if (doB) { BURST(acc0, h1s, 1032, 512, bw0) act0 = true; } }
      else { if (doB) { BURST(acc0, h1s, 1032, 512, bw0) act0 = true; } }
      if (act0) {
#pragma unroll
        for (int r = 0; r < 4; ++r) gls[q0][fr][(lane >> 4) * 4 + r] = acc0[r];
      }
      if (act1) {
#pragma unroll
        for (int r = 0; r < 4; ++r) gls[q0 + 1][fr][(lane >> 4) * 4 + r] = acc1[r];
      }
      __syncthreads();

      if (s < 127) {
#pragma unroll
        for (int jj = 0; jj < 2; ++jj) *(uint4*)&xe[sm * 520 + skq + jj * 256] = re[jj];
      }

      if (tid < 128) {
        const int jp = w8 + gdj;
        if (doA) {
          float gi = gls[0][gdj][gb] + gls[2][gdj][gb] + gls[4][gdj][gb] + cpA0;
          float gf = gls[0][8 + gdj][gb] + gls[2][8 + gdj][gb] + gls[4][8 + gdj][gb] + cpA1;
          float gg = gls[1][gdj][gb] + gls[3][gdj][gb] + gls[5][gdj][gb] + cpA2;
          float go = gls[1][8 + gdj][gb] + gls[3][8 + gdj][gb] + gls[5][8 + gdj][gb] + cpA3;
          c0r = sigf(gf) * c0r + sigf(gi) * tanh_(gg);
          float h = sigf(go) * tanh_(c0r);
          st_cv16(xr + (size_t)(s + 1) * 16384 + gb * 1024 + jp, f2bf(h));
        }
        if (doB) {
          float gi = gls[6][gdj][gb] + gls[8][gdj][gb] + gls[10][gdj][gb] +
                     gls[12][gdj][gb] + cpB0;
          float gf = gls[6][8 + gdj][gb] + gls[8][8 + gdj][gb] + gls[10][8 + gdj][gb] +
                     gls[12][8 + gdj][gb] + cpB1;
          float gg = gls[7][gdj][gb] + gls[9][gdj][gb] + gls[11][gdj][gb] +
                     gls[13][gdj][gb] + cpB2;
          float go = gls[7][8 + gdj][gb] + gls[9][8 + gdj][gb] + gls[11][8 + gdj][gb] +
                     gls[13][8 + gdj][gb] + cpB3;
          c1r = sigf(gf) * c1r + sigf(gi) * tanh_(gg);
          float h = sigf(go) * tanh_(c1r);
          st_cv16(h1r + (size_t)s * 16384 + gb * 1024 + jp, f2bf(h));
          // WRITE-THROUGH: fc blocks on other XCDs consume within this kernel
          st_cv16(out2b + ((s - 1) * 16 + gb) * 1024 + jp, f2bf(tanh_(h)));
        }
      }
      gsyncf(++step, bar);
    }
  } else {
    // ======================= fc path (shadow GEMM) =========================
    u16 (*Al)[40] = (u16(*)[40])smem;                   // [128][40]
    u16 (*Bl)[40] = (u16(*)[40])(smem + 10240);         // [256][40]

    const int fb = wgid - NBLK;        // 0..124
    const int n0 = fb * 256;

    // convert private fcw slice fp32 -> bf16 (replaces prep_bf16 kernel)
    for (int i = tid; i < 32768; i += 512) {
      const int row = i >> 7;          // 0..255
      const int c8 = (i & 127) * 8;
      const float* s = fcw + (size_t)(n0 + row) * 1024 + c8;
      bf16x8 v = cvt8(*(const float4*)s, *(const float4*)(s + 4));
      *(uint4*)(fcwb + (size_t)(n0 + row) * 1024 + c8) = __builtin_bit_cast(uint4, v);
    }
    __syncthreads();

    const int wm = (wave & 1) * 64;
    const int wn = (wave >> 1) * 64;
    float bj[4];
#pragma unroll
    for (int j = 0; j < 4; ++j) bj[j] = fcb[n0 + wn + j * 16 + fr];

    const int rA = tid >> 2, cA = (tid & 3) * 8;    // A stage: 128r x 32c
    const int rB = tid >> 1, cB = (tid & 1) * 16;   // B stage: 256r x 32c
    const u16* Bs = fcwb + (size_t)(n0 + rB) * 1024 + cB;
    const int mrb = (lane >> 4) * 4;

    for (int m0 = 0; m0 < 16; ++m0) {
      // out2 rows t in [m0*8, m0*8+7] drained once agg flag >= m0*8+10.
      wait_agg((unsigned)(m0 * 8 + 10), bar);

      f32x4 acc[4][4] = {};
      const u16* Ag = out2b + (size_t)(m0 * 128 + rA) * 1024 + cA;
      for (int k0 = 0; k0 < 1024; k0 += 32) {
        uint4 av = *(const uint4*)(Ag + k0);         // plain cached (gated)
        uint4 b0 = *(const uint4*)(Bs + k0);         // own-converted, own L2
        uint4 b1 = *(const uint4*)(Bs + k0 + 8);
        __syncthreads();
        *(uint4*)&Al[rA][cA] = av;
        *(uint4*)&Bl[rB][cB] = b0;
        *(uint4*)&Bl[rB][cB + 8] = b1;
        __syncthreads();

        bf16x8 af[4], bf[4];
#pragma unroll
        for (int i = 0; i < 4; ++i) af[i] = *(const bf16x8*)&Al[wm + i * 16 + fr][ks8];
#pragma unroll
        for (int j = 0; j < 4; ++j) bf[j] = *(const bf16x8*)&Bl[wn + j * 16 + fr][ks8];
#pragma unroll
        for (int i = 0; i < 4; ++i)
#pragma unroll
          for (int j = 0; j < 4; ++j)
            acc[i][j] = __builtin_amdgcn_mfma_f32_16x16x32_bf16(af[i], bf[j], acc[i][j], 0, 0, 0);
      }

#pragma unroll
      for (int i = 0; i < 4; ++i) {
#pragma unroll
        for (int r = 0; r < 4; ++r) {
          const int m = m0 * 128 + wm + i * 16 + mrb + r;
          float* dst = logits + ((size_t)(m & 15) * 128 + (m >> 4)) * 32000;
#pragma unroll
          for (int j = 0; j < 4; ++j) {
            dst[n0 + wn + j * 16 + fr] = acc[i][j][r] + bj[j];
          }
        }
      }
    }
  }
}

// fallback fc (fp32 B, converts per tile) — used only if ws too small.
__global__ __launch_bounds__(256, 2) void fc_gemm_mfma(
    const u16* __restrict__ A, const float* __restrict__ Bw,
    const float* __restrict__ bias, float* __restrict__ C) {
  __shared__ __align__(16) u16 Al[128][40];
  __shared__ __align__(16) u16 Bl[128][40];
  const int tid = threadIdx.x;
  const int m0 = blockIdx.x * 128;
  const int n0 = blockIdx.y * 128;
  const int wave = tid >> 6;
  const int lane = tid & 63;
  const int wm = (wave & 1) * 64;
  const int wn = (wave >> 1) * 64;
  const int fr = lane & 15;
  const int ks = lane >> 4;
  const int srow = tid >> 1;
  const int sh16 = (tid & 1) * 16;
  const u16* Ag = A + (size_t)(m0 + srow) * 1024 + sh16;
  const float* Bg = Bw + (size_t)(n0 + srow) * 1024 + sh16;
  f32x4 acc[4][4] = {};
  for (int k0 = 0; k0 < 1024; k0 += 32) {
    uint4 a0 = *(const uint4*)(Ag + k0);
    uint4 a1 = *(const uint4*)(Ag + k0 + 8);
    float bfv[16];
    *(float4*)&bfv[0] = *(const float4*)(Bg + k0);
    *(float4*)&bfv[4] = *(const float4*)(Bg + k0 + 4);
    *(float4*)&bfv[8] = *(const float4*)(Bg + k0 + 8);
    *(float4*)&bfv[12] = *(const float4*)(Bg + k0 + 12);
    u16 bu[16];
#pragma unroll
    for (int u = 0; u < 16; ++u) bu[u] = f2bf(bfv[u]);
    __syncthreads();
    *(uint4*)&Al[srow][sh16] = a0;
    *(uint4*)&Al[srow][sh16 + 8] = a1;
    *(uint4*)&Bl[srow][sh16] = *(uint4*)&bu[0];
    *(uint4*)&Bl[srow][sh16 + 8] = *(uint4*)&bu[8];
    __syncthreads();
    bf16x8 af[4], bf[4];
#pragma unroll
    for (int i = 0; i < 4; ++i) af[i] = *(const bf16x8*)&Al[wm + i * 16 + fr][ks * 8];
#pragma unroll
    for (int j = 0; j < 4; ++j) bf[j] = *(const bf16x8*)&Bl[wn + j * 16 + fr][ks * 8];
#pragma unroll
    for (int i = 0; i < 4; ++i)
#pragma unroll
      for (int j = 0; j < 4; ++j)
        acc[i][j] = __builtin_amdgcn_mfma_f32_16x16x32_bf16(af[i], bf[j], acc[i][j], 0, 0, 0);
  }
  float bj[4];
#pragma unroll
  for (int j = 0; j < 4; ++j) bj[j] = bias[n0 + wn + j * 16 + fr];
  const int mrb = (lane >> 4) * 4;
#pragma unroll
  for (int i = 0; i < 4; ++i) {
#pragma unroll
    for (int r = 0; r < 4; ++r) {
      const int m = m0 + wm + i * 16 + mrb + r;
      float* dst = C + ((size_t)(m & 15) * 128 + (m >> 4)) * 32000;
#pragma unroll
      for (int j = 0; j < 4; ++j) dst[n0 + wn + j * 16 + fr] = acc[i][j][r] + bj[j];
    }
  }
}

extern "C" void kernel_launch(void* const* d_in, const int* in_sizes, int n_in,
                              void* d_out, int out_size, void* d_ws, size_t ws_size,
                              hipStream_t stream) {
  const float* enc_h = (const float*)d_in[0];
  const float* enc_c = (const float*)d_in[1];
  const int* tgt = (const int*)d_in[2];
  const float* emb = (const float*)d_in[3];
  const float* wih0 = (const float*)d_in[4];
  const float* whh0 = (const float*)d_in[5];
  const float* bih0 = (const float*)d_in[6];
  const float* bhh0 = (const float*)d_in[7];
  const float* wih1 = (const float*)d_in[8];
  const float* whh1 = (const float*)d_in[9];
  const float* bih1 = (const float*)d_in[10];
  const float* bhh1 = (const float*)d_in[11];
  const float* fcw = (const float*)d_in[12];
  const float* fcb = (const float*)d_in[13];
  float* logits = (float*)d_out;

  unsigned* bar = (unsigned*)d_ws;  // 32 KB barrier region (flags @128B stride)
  hipMemsetAsync(d_ws, 0, 32768, stream);

  // ws layout: bar 32K | cp 256K | x0b 2M | xr 4.125M | h1r 4.125M |
  //            out2b 4M | fcwb 65.5M  (total ~80.6 MB)
  float* cp = (float*)((char*)d_ws + 32768);
  u16* x0b = (u16*)(cp + 65536);
  u16* xr = x0b + 1048576;
  u16* h1r = xr + 2113536;
  u16* out2b = h1r + 2113536;
  u16* fcwb = out2b + 2097152;
  const bool fused = (ws_size >= 80576512ull);

  prep_emb<<<512, 256, 0, stream>>>(tgt, emb, x0b);
  prep_ctx2<<<256, 256, 0, stream>>>(enc_h, wih0, cp);
  if (fused) {
    dec_fc<<<NBLK + NFCB, 512, 0, stream>>>(enc_h, enc_c, wih0, whh0, wih1, whh1,
                                            bih0, bhh0, bih1, bhh1, cp, x0b,
                                            xr, h1r, out2b, fcw, fcb, fcwb,
                                            logits, bar);
  } else {
    dec_fc<<<NBLK, 512, 0, stream>>>(enc_h, enc_c, wih0, whh0, wih1, whh1,
                                     bih0, bhh0, bih1, bhh1, cp, x0b,
                                     xr, h1r, out2b, fcw, fcb, fcwb,
                                     logits, bar);
    fc_gemm_mfma<<<dim3(16, 250), 256, 0, stream>>>(out2b, fcw, fcb, logits);
  }
}